// Round 16
// baseline (2687.528 us; speedup 1.0000x reference)
//
#include <hip/hip_runtime.h>
#include <hip/hip_bf16.h>

#define B_ 16
#define T_ 32
#define S_ 256
#define K_ 8
#define L_ 64
#define V_ 32000
#define VX_ 32050
#define NEG_ -1e10f
#define NBLK_ 64
#define BARSTRIDE_ 288   // 8 groups x 32 u32 + root word

typedef __attribute__((ext_vector_type(8))) __bf16 bf16x8;
typedef __attribute__((ext_vector_type(8))) unsigned short us8;
typedef __attribute__((ext_vector_type(4))) float f32x4;

__device__ __forceinline__ float fsigmoid(float x){ return 1.f/(1.f+__expf(-x)); }
__device__ __forceinline__ float ftanh(float x){ float e=__expf(2.f*x); return 1.f - 2.f/(e+1.f); }
__device__ __forceinline__ unsigned short bf16rne(float f){
  unsigned u = __float_as_uint(f);
  u = u + 0x7FFFu + ((u >> 16) & 1u);
  return (unsigned short)(u >> 16);
}

// ---- LLC-coherent access helpers (device scope via sc0 sc1) ----
__device__ __forceinline__ unsigned ld_llc_u32(const unsigned* p){
  unsigned v;
  asm volatile("global_load_dword %0, %1, off sc0 sc1\n\ts_waitcnt vmcnt(0)" : "=&v"(v) : "v"(p));
  return v;
}
__device__ __forceinline__ float ld_llc_f(const float* p){
  float v;
  asm volatile("global_load_dword %0, %1, off sc0 sc1\n\ts_waitcnt vmcnt(0)" : "=&v"(v) : "v"(p));
  return v;
}
__device__ __forceinline__ f32x4 ld_llc_f4(const float* p){
  f32x4 v;
  asm volatile("global_load_dwordx4 %0, %1, off sc0 sc1\n\ts_waitcnt vmcnt(0)" : "=&v"(v) : "v"(p));
  return v;
}
__device__ __forceinline__ void ld_llc_f4x2(const float* p, f32x4& a, f32x4& b){
  asm volatile("global_load_dwordx4 %0, %2, off sc0 sc1\n\t"
               "global_load_dwordx4 %1, %2, off offset:16 sc0 sc1\n\t"
               "s_waitcnt vmcnt(0)"
               : "=&v"(a), "=&v"(b) : "v"(p));
}
__device__ __forceinline__ void st_llc_f(float* p, float v){
  asm volatile("global_store_dword %0, %1, off sc0 sc1" :: "v"(p), "v"(v) : "memory");
}

// ---- tree barrier: 8 parallel group counters (8 arrivals each) + root (8 arrivals) ----
__device__ __forceinline__ void pbar(unsigned* base, int blk){
  asm volatile("s_waitcnt vmcnt(0)" ::: "memory");
  __syncthreads();
  if (threadIdx.x == 0){
    unsigned* g = base + (blk & 7)*32;
    unsigned* root = base + 256;
    unsigned old = __hip_atomic_fetch_add(g, 1u, __ATOMIC_RELAXED, __HIP_MEMORY_SCOPE_AGENT);
    if (old == 7u)
      __hip_atomic_fetch_add(root, 1u, __ATOMIC_RELAXED, __HIP_MEMORY_SCOPE_AGENT);
    while (ld_llc_u32(root) < 8u) __builtin_amdgcn_s_sleep(1);
  }
  __syncthreads();
}

// ================= merged prep: embed ∥ PVS-GEMM ∥ PVK-GEMM ∥ GIY-GEMM(embed-gather) =================
__global__ __launch_bounds__(256) void k_prep(const float* __restrict__ emb, const int* __restrict__ tgt,
    const float* __restrict__ src, const float* __restrict__ Wv_c, const float* __restrict__ bv_c,
    const float* __restrict__ kgh, const float* __restrict__ Wv_k, const float* __restrict__ bv_k,
    const float* __restrict__ W_ih,
    float* __restrict__ Xb, float* __restrict__ PVS, float* __restrict__ PVK, float* __restrict__ GIY){
  const int bid = blockIdx.x, tid = threadIdx.x;
  if (bid >= 360){   // embed fill: X[t][b][0:512] = emb[tgt[b][t]]
    int idx = (bid-360)*256 + tid;
    int t = idx >> 13; int b = (idx >> 9) & 15; int e = idx & 511;
    int tok = tgt[b*T_ + t];
    Xb[(size_t)(t*B_+b)*1536 + e] = emb[(size_t)tok*512 + e];
    return;
  }
  __shared__ float As[16][132];
  __shared__ float Ws[16][68];
  const float *A, *W, *bias; float* C; int ldA, ldW, ldC, m0, n0; bool gather = false;
  if (bid < 256){      A=src; ldA=512; W=Wv_c; ldW=512; bias=bv_c; C=PVS; ldC=512;
                       m0=(bid&31)*128; n0=(bid>>5)*64; }
  else if (bid < 264){ A=kgh; ldA=512; W=Wv_k; ldW=512; bias=bv_k; C=PVK; ldC=512;
                       m0=0; n0=(bid-256)*64; }
  else {               gather=true; A=nullptr; ldA=0; W=W_ih; ldW=1536; bias=nullptr; C=GIY; ldC=1536;
                       int g=bid-264; m0=(g&3)*128; n0=(g>>2)*64; }
  const int tm = tid & 15, tn = tid >> 4;
  float acc[8][4];
#pragma unroll
  for (int i=0;i<8;++i)
#pragma unroll
    for(int j=0;j<4;++j) acc[i][j]=0.f;
  for (int k0=0;k0<512;k0+=16){
#pragma unroll
    for (int rr=0;rr<2;++rr){
      int f = tid + rr*256;
      int mm = f >> 2, kc = f & 3;
      int m = m0 + mm;
      const float* ap;
      if (gather){
        int tok = tgt[(m & 15)*T_ + (m >> 4)];
        ap = emb + (size_t)tok*512 + k0 + kc*4;
      } else {
        ap = A + (size_t)m*ldA + k0 + kc*4;
      }
      const float4 v = *(const float4*)ap;
      As[kc*4+0][mm]=v.x; As[kc*4+1][mm]=v.y; As[kc*4+2][mm]=v.z; As[kc*4+3][mm]=v.w;
    }
    {
      int nn = tid >> 2, kc = tid & 3;
      const float4 v = *(const float4*)(W + (size_t)(n0+nn)*ldW + k0 + kc*4);
      Ws[kc*4+0][nn]=v.x; Ws[kc*4+1][nn]=v.y; Ws[kc*4+2][nn]=v.z; Ws[kc*4+3][nn]=v.w;
    }
    __syncthreads();
#pragma unroll
    for (int kk=0;kk<16;++kk){
      float a[8], w[4];
      float4 a0 = *(const float4*)&As[kk][tm*8];
      float4 a1 = *(const float4*)&As[kk][tm*8+4];
      float4 w0 = *(const float4*)&Ws[kk][tn*4];
      a[0]=a0.x;a[1]=a0.y;a[2]=a0.z;a[3]=a0.w;a[4]=a1.x;a[5]=a1.y;a[6]=a1.z;a[7]=a1.w;
      w[0]=w0.x;w[1]=w0.y;w[2]=w0.z;w[3]=w0.w;
#pragma unroll
      for (int i=0;i<8;++i)
#pragma unroll
        for (int j=0;j<4;++j) acc[i][j] += a[i]*w[j];
    }
    __syncthreads();
  }
#pragma unroll
  for (int i=0;i<8;++i){
    int m = m0 + tm*8 + i;
#pragma unroll
    for (int j=0;j<4;++j){
      int n = n0 + tn*4 + j;
      C[(size_t)m*ldC + n] = acc[i][j] + (bias ? bias[n] : 0.f);
    }
  }
}

// ================= persistent recurrence v7: 64 blocks x 512, v4-style phases =================
struct RP7 {
  const float *inith, *src, *smask, *kgh, *kmask;
  const float *Wq_c, *Wq_k, *Vw_c, *bV_c, *Vw_k, *bV_k;
  const float *W_ih, *W_hh, *b_ih, *b_hh;
  const float *PVS, *PVK, *GIY;
  float *Xb, *S_all, *KW;
  float *HQC, *HQK, *GH, *CK, *Hbuf, *Eg;
  unsigned *cnt;
};

__global__ __launch_bounds__(512) void k_recur7(RP7 p){
  __shared__ float SH[4992];
  const int tid = threadIdx.x;
  const int blk = blockIdx.x;
  const float bVc = p.bV_c[0], bVk = p.bV_k[0];

  for (int t = 0; t < T_; ++t){
    // ======== P1: HQ/GH — block = (rg 0..15) x (bg 0..3): rows rg*160..+160, batches bg*4..+4 ========
    {
      const int rg = blk & 15, bg = blk >> 4;
      float* hS = SH;   // 4 x 516
      {
        int i0 = tid*4; int bb = i0 >> 9, cc = i0 & 511;
        float vx,vy,vz,vw;
        if (t == 0){
          float4 v = *(const float4*)(p.inith + (size_t)(bg*4+bb)*512 + cc);
          vx=v.x; vy=v.y; vz=v.z; vw=v.w;
        } else {
          f32x4 v = ld_llc_f4(p.Hbuf + (size_t)(bg*4+bb)*512 + cc);
          vx=v[0]; vy=v[1]; vz=v[2]; vw=v[3];
        }
        hS[bb*516+cc]=vx; hS[bb*516+cc+1]=vy; hS[bb*516+cc+2]=vz; hS[bb*516+cc+3]=vw;
      }
      __syncthreads();
      int rl = tid >> 2, bl = tid & 3;
      int b = bg*4 + bl;
      const float* hb = hS + bl*516;
#pragma unroll
      for (int it = 0; it < 2; ++it){
        int rr2 = rl + it*128;
        if (rr2 < 160){
          int R = rg*160 + rr2;
          const float* wrow = (R < 512) ? (p.Wq_c + (size_t)R*512)
                            : (R < 1024) ? (p.Wq_k + (size_t)(R-512)*512)
                            : (p.W_hh + (size_t)(R-1024)*512);
          float s = 0.f;
#pragma unroll 8
          for (int m=0;m<128;++m){
            float4 w = *(const float4*)(wrow + m*4);
            float4 hv = *(const float4*)(hb + m*4);
            s += w.x*hv.x + w.y*hv.y + w.z*hv.z + w.w*hv.w;
          }
          if (R < 512)       st_llc_f(p.HQC + b*512 + R, s);
          else if (R < 1024) st_llc_f(p.HQK + b*512 + (R-512), s);
          else               st_llc_f(p.GH + b*1536 + (R-1024), s + p.b_hh[R-1024]);
        }
      }
    }
    pbar(p.cnt + (4*t)*BARSTRIDE_, blk);
    __syncthreads();

    // ======== P2: e_src — block = (b 0..15) x (pg 0..3): positions pg*64..+64, 8 thr/row ========
    {
      const int b2 = blk >> 2, pg = blk & 3;
      float* hqcS = SH;        // 8 chunks x 65 = 520
      float* vwcS = SH + 520;
      {
        int chunk = tid >> 6, ii = tid & 63;
        hqcS[chunk*65+ii] = ld_llc_f(p.HQC + b2*512 + tid);
        vwcS[chunk*65+ii] = p.Vw_c[tid];
      }
      __syncthreads();
      int pp = tid >> 3, q = tid & 7;
      int s_i = pg*64 + pp;
      const float4* pv4 = (const float4*)(p.PVS + ((size_t)(b2*S_ + s_i))*512 + q*64);
      const float* hq = hqcS + q*65;
      const float* vw = vwcS + q*65;
      float pe = 0.f;
#pragma unroll
      for (int m=0;m<16;++m){
        float4 v = pv4[m];
        int i0 = m*4;
        pe += ftanh(v.x+hq[i0+0])*vw[i0+0] + ftanh(v.y+hq[i0+1])*vw[i0+1]
            + ftanh(v.z+hq[i0+2])*vw[i0+2] + ftanh(v.w+hq[i0+3])*vw[i0+3];
      }
      pe += __shfl_down(pe, 4, 8);
      pe += __shfl_down(pe, 2, 8);
      pe += __shfl_down(pe, 1, 8);
      if (q == 0){
        float v = pe + bVc;
        if (p.smask[b2*S_ + s_i] == 0.f) v += NEG_;
        st_llc_f(p.Eg + b2*S_ + s_i, v);
      }
    }
    pbar(p.cnt + (4*t+1)*BARSTRIDE_, blk);
    __syncthreads();

    // ======== P3: softmax + c_t/k_t — block = (b 0..15) x (jg 0..3): cols jg*128..+128 ========
    {
      const int b3 = blk >> 2, jg = blk & 3, j0 = jg*128;
      float* eS    = SH;          // 256
      float* wS    = SH + 256;    // 256
      float* hqkS  = SH + 512;    // 64x9 = 576
      float* vwkS  = SH + 1088;   // 576
      float* partS = SH + 1664;   // 512
      float* ekS   = SH + 2176;   // 8
      float* kwS   = SH + 2184;   // 8
      float* MZ    = SH + 2192;   // 2
      if (tid < 64){
        f32x4 v = ld_llc_f4(p.Eg + b3*S_ + tid*4);
        eS[tid*4]=v[0]; eS[tid*4+1]=v[1]; eS[tid*4+2]=v[2]; eS[tid*4+3]=v[3];
      }
      {
        int part = tid >> 3, ii = tid & 7;
        hqkS[part*9+ii] = ld_llc_f(p.HQK + b3*512 + tid);
        vwkS[part*9+ii] = p.Vw_k[tid];
      }
      __syncthreads();
      if (tid < 64){
        float4 e4 = *(const float4*)&eS[tid*4];
        float m = fmaxf(fmaxf(e4.x,e4.y), fmaxf(e4.z,e4.w));
#pragma unroll
        for (int off=32; off>0; off>>=1) m = fmaxf(m, __shfl_xor(m, off, 64));
        float z = __expf(e4.x-m)+__expf(e4.y-m)+__expf(e4.z-m)+__expf(e4.w-m);
#pragma unroll
        for (int off=32; off>0; off>>=1) z += __shfl_xor(z, off, 64);
        if (tid == 0){ MZ[0] = m; MZ[1] = z; }
      }
      {
        int key = tid >> 6, part = tid & 63;
        const float4* pk4 = (const float4*)(p.PVK + ((size_t)(b3*K_ + key))*512 + part*8);
        float4 va = pk4[0], vb = pk4[1];
        const float* hq = hqkS + part*9;
        const float* vw = vwkS + part*9;
        float s2 = ftanh(va.x+hq[0])*vw[0] + ftanh(va.y+hq[1])*vw[1]
                 + ftanh(va.z+hq[2])*vw[2] + ftanh(va.w+hq[3])*vw[3]
                 + ftanh(vb.x+hq[4])*vw[4] + ftanh(vb.y+hq[5])*vw[5]
                 + ftanh(vb.z+hq[6])*vw[6] + ftanh(vb.w+hq[7])*vw[7];
#pragma unroll
        for (int off=32; off>0; off>>=1) s2 += __shfl_xor(s2, off, 64);
        if (part == 0){
          float v = s2 + bVk;
          if (p.kmask[b3*K_ + key] == 0.f) v += NEG_;
          ekS[key] = v;
        }
      }
      __syncthreads();
      if (tid == 0){
        float mk = -1e30f;
#pragma unroll
        for (int k=0;k<8;++k) mk = fmaxf(mk, ekS[k]);
        float z = 0.f; float tmp[8];
#pragma unroll
        for (int k=0;k<8;++k){ tmp[k] = __expf(ekS[k]-mk); z += tmp[k]; }
        float iz = 1.f/z;
#pragma unroll
        for (int k=0;k<8;++k) kwS[k] = tmp[k]*iz;
      }
      __syncthreads();
      float Mv = MZ[0], invZ = 1.f/MZ[1];
      if (tid < 256) wS[tid] = __expf(eS[tid]-Mv);
      __syncthreads();
      {
        // 4 groups x 64 positions each (S=256 total); jl covers the 128-col slice
        int sg = tid >> 7, jl = tid & 127;
        const float* sp = p.src + ((size_t)(b3*S_ + sg*64))*512 + j0 + jl;
        float acc = 0.f;
#pragma unroll 8
        for (int i=0;i<64;++i) acc += wS[sg*64+i] * sp[(size_t)i*512];
        partS[sg*128 + jl] = acc;
      }
      __syncthreads();
      if (tid < 128){
        float c = partS[tid] + partS[128 + tid] + partS[256 + tid] + partS[384 + tid];
        c *= invZ;
        float kt = 0.f;
#pragma unroll
        for (int k=0;k<8;++k) kt += kwS[k] * p.kgh[((size_t)(b3*K_+k))*512 + j0 + tid];
        float* Xbt = p.Xb + ((size_t)t*16 + b3)*1536;
        Xbt[512 + j0 + tid]  = c;
        Xbt[1024 + j0 + tid] = kt;
        st_llc_f(p.CK + b3*1024 + j0 + tid, c);
        st_llc_f(p.CK + b3*1024 + 512 + j0 + tid, kt);
      }
      if (jg == 0 && tid < 8) p.KW[t*128 + b3*8 + tid] = kwS[tid];
    }
    pbar(p.cnt + (4*t+2)*BARSTRIDE_, blk);
    __syncthreads();

    // ======== P4: GRU — block = (rg2 0..15) x (bg2 0..3): cols rg2*32..+32, batches bg2*4..+4 ========
    {
      const int rg2 = blk & 15, bg2 = blk >> 4;
      const int j0 = rg2*32, bb0 = bg2*4;
      float* ckS = SH;          // 4 x 1028 = 4112
      float* giS = SH + 4112;   // 96 x 4 = 384
      float* ghS = SH + 4496;   // 96 x 4 = 384
      {
        int i0 = tid*8; int bb = i0 >> 10, cc = i0 & 1023;
        f32x4 a, b4;
        ld_llc_f4x2(p.CK + (size_t)(bb0+bb)*1024 + cc, a, b4);
        float* d = ckS + bb*1028 + cc;
        d[0]=a[0]; d[1]=a[1]; d[2]=a[2]; d[3]=a[3];
        d[4]=b4[0]; d[5]=b4[1]; d[6]=b4[2]; d[7]=b4[3];
      }
      __syncthreads();
      int pair = tid >> 1, ks = tid & 1;
#pragma unroll
      for (int it = 0; it < 2; ++it){
        int pr = pair + it*256;           // tasks 0..383 (wave-uniform branch: it=1 -> tid<256)
        if (pr < 384){
          int rw = pr >> 2, bloc = pr & 3;     // rw 0..95: gate = rw>>5, col = rw&31
          int row = (rw >> 5)*512 + j0 + (rw & 31);
          const float4* wi4 = (const float4*)(p.W_ih + (size_t)row*1536 + 512 + ks*512);
          const float* ckb = ckS + bloc*1028 + ks*512;
          float gi = 0.f;
#pragma unroll 8
          for (int m=0;m<128;++m){
            float4 w = wi4[m];
            gi += w.x*ckb[m*4] + w.y*ckb[m*4+1] + w.z*ckb[m*4+2] + w.w*ckb[m*4+3];
          }
          gi += __shfl_xor(gi, 1, 64);
          if (ks == 0){
            int b = bb0 + bloc;
            giS[rw*4 + bloc] = gi + p.GIY[((size_t)t*16 + b)*1536 + row] + p.b_ih[row];
            ghS[rw*4 + bloc] = ld_llc_f(p.GH + b*1536 + row);
          }
        }
      }
      __syncthreads();
      if (tid < 128){
        int jl = tid >> 2, bl2 = tid & 3;    // jl 0..31
        int b = bb0 + bl2, j = j0 + jl;
        float gir = giS[jl*4+bl2],      giz = giS[(32+jl)*4+bl2],  gin = giS[(64+jl)*4+bl2];
        float ghr = ghS[jl*4+bl2],      ghz = ghS[(32+jl)*4+bl2],  ghn = ghS[(64+jl)*4+bl2];
        float r = fsigmoid(gir + ghr);
        float z = fsigmoid(giz + ghz);
        float n = ftanh(gin + r*ghn);
        float hold = (t == 0) ? p.inith[b*512 + j] : ld_llc_f(p.Hbuf + b*512 + j);
        float hn = (1.f - z)*n + z*hold;
        p.S_all[((size_t)t*16 + b)*512 + j] = hn;
        st_llc_f(p.Hbuf + b*512 + j, hn);
      }
    }
    pbar(p.cnt + (4*t+3)*BARSTRIDE_, blk);
    __syncthreads();
  }
}

// ================= merged epilogue-1: W1-GEMM(CAT-gather) ∥ Qb-GEMM ∥ ptr =================
__global__ __launch_bounds__(256) void k_epi(const float* __restrict__ S_all, const float* __restrict__ X,
    const float* __restrict__ kgf, const float* __restrict__ W1, const float* __restrict__ b1,
    const float* __restrict__ Wcpy, const float* __restrict__ bcpy,
    const float* __restrict__ Wptr, const float* __restrict__ bptr,
    float* __restrict__ HID, float* __restrict__ Qb, float* __restrict__ PTR){
  const int bid = blockIdx.x, tid = threadIdx.x;
  if (bid >= 64){   // ptr: rows (bid-64)*4 .. +4
    int r = (bid-64)*4 + (tid >> 6);
    int lane = tid & 63;
    const float* seg[5];
    seg[0] = X + (size_t)r*1536 + 512;
    seg[1] = S_all + (size_t)r*512;
    seg[2] = X + (size_t)r*1536;
    seg[3] = kgf + (size_t)(r & 15)*512;
    seg[4] = X + (size_t)r*1536 + 1024;
    float s = 0.f;
#pragma unroll
    for (int g=0; g<5; ++g){
      const float* p = seg[g];
      const float* w = Wptr + g*512;
#pragma unroll
      for (int m=0;m<8;++m){ int i = lane + m*64; s += p[i]*w[i]; }
    }
#pragma unroll
    for (int off=32;off>0;off>>=1) s += __shfl_down(s, off, 64);
    if (lane == 0) PTR[r] = fsigmoid(s + bptr[0]);
    return;
  }
  __shared__ float As[16][132];
  __shared__ float Ws[16][68];
  const bool isW1 = (bid < 32);
  const int g = isW1 ? bid : bid-32;
  const int m0 = (g&3)*128, n0 = (g>>2)*64;
  const int KK = isW1 ? 2048 : 512;
  const float* W = isW1 ? W1 : Wcpy;
  const float* bias = isW1 ? b1 : bcpy;
  float* C = isW1 ? HID : Qb;
  const int tm = tid & 15, tn = tid >> 4;
  float acc[8][4];
#pragma unroll
  for (int i=0;i<8;++i)
#pragma unroll
    for(int j=0;j<4;++j) acc[i][j]=0.f;
  for (int k0=0;k0<KK;k0+=16){
#pragma unroll
    for (int rr=0;rr<2;++rr){
      int f = tid + rr*256;
      int mm = f >> 2, kc = f & 3;
      int m = m0 + mm, col = k0 + kc*4;
      const float* ap;
      if (!isW1)            ap = S_all + (size_t)m*512 + col;
      else if (col < 512)   ap = S_all + (size_t)m*512 + col;
      else if (col < 1536)  ap = X + (size_t)m*1536 + col;
      else                  ap = kgf + (size_t)(m & 15)*512 + (col - 1536);
      const float4 v = *(const float4*)ap;
      As[kc*4+0][mm]=v.x; As[kc*4+1][mm]=v.y; As[kc*4+2][mm]=v.z; As[kc*4+3][mm]=v.w;
    }
    {
      int nn = tid >> 2, kc = tid & 3;
      const float4 v = *(const float4*)(W + (size_t)(n0+nn)*KK + k0 + kc*4);
      Ws[kc*4+0][nn]=v.x; Ws[kc*4+1][nn]=v.y; Ws[kc*4+2][nn]=v.z; Ws[kc*4+3][nn]=v.w;
    }
    __syncthreads();
#pragma unroll
    for (int kk=0;kk<16;++kk){
      float a[8], w[4];
      float4 a0 = *(const float4*)&As[kk][tm*8];
      float4 a1 = *(const float4*)&As[kk][tm*8+4];
      float4 w0 = *(const float4*)&Ws[kk][tn*4];
      a[0]=a0.x;a[1]=a0.y;a[2]=a0.z;a[3]=a0.w;a[4]=a1.x;a[5]=a1.y;a[6]=a1.z;a[7]=a1.w;
      w[0]=w0.x;w[1]=w0.y;w[2]=w0.z;w[3]=w0.w;
#pragma unroll
      for (int i=0;i<8;++i)
#pragma unroll
        for (int j=0;j<4;++j) acc[i][j] += a[i]*w[j];
    }
    __syncthreads();
  }
#pragma unroll
  for (int i=0;i<8;++i){
    int m = m0 + tm*8 + i;
#pragma unroll
    for (int j=0;j<4;++j){
      int n = n0 + tn*4 + j;
      C[(size_t)m*512 + n] = acc[i][j] + bias[n];
    }
  }
}

// ============ bf16 MFMA logits GEMM, f32 inputs converted inline (verified) ============
__global__ __launch_bounds__(512) void k_logits(const float* __restrict__ A,
    const float* __restrict__ Bf, const float* __restrict__ bias, float* __restrict__ out){
  __shared__ unsigned short As[256][72];
  __shared__ unsigned short Bs[128][72];
  const int tid = threadIdx.x;
  const int m0 = blockIdx.x*256, n0 = blockIdx.y*128;
  const int lane = tid & 63, wid = tid >> 6;
  const int mw = wid >> 1, nw = wid & 1;
  f32x4 acc[4][4];
#pragma unroll
  for (int i=0;i<4;++i)
#pragma unroll
    for (int j=0;j<4;++j) acc[i][j] = (f32x4){0.f,0.f,0.f,0.f};
  for (int k0 = 0; k0 < 512; k0 += 64){
#pragma unroll
    for (int i=0;i<4;++i){
      int v = i*512 + tid; int row = v >> 3, vc = v & 7;
      const float* srcp = A + (size_t)(m0+row)*512 + k0 + vc*8;
      float4 f0 = *(const float4*)srcp, f1 = *(const float4*)(srcp+4);
      us8 d;
      d[0]=bf16rne(f0.x); d[1]=bf16rne(f0.y); d[2]=bf16rne(f0.z); d[3]=bf16rne(f0.w);
      d[4]=bf16rne(f1.x); d[5]=bf16rne(f1.y); d[6]=bf16rne(f1.z); d[7]=bf16rne(f1.w);
      *(us8*)&As[row][vc*8] = d;
    }
#pragma unroll
    for (int i=0;i<2;++i){
      int v = i*512 + tid; int row = v >> 3, vc = v & 7;
      const float* srcp = Bf + (size_t)(n0+row)*512 + k0 + vc*8;
      float4 f0 = *(const float4*)srcp, f1 = *(const float4*)(srcp+4);
      us8 d;
      d[0]=bf16rne(f0.x); d[1]=bf16rne(f0.y); d[2]=bf16rne(f0.z); d[3]=bf16rne(f0.w);
      d[4]=bf16rne(f1.x); d[5]=bf16rne(f1.y); d[6]=bf16rne(f1.z); d[7]=bf16rne(f1.w);
      *(us8*)&Bs[row][vc*8] = d;
    }
    __syncthreads();
#pragma unroll
    for (int kk=0;kk<2;++kk){
      bf16x8 a[4], bf[4];
#pragma unroll
      for (int mi=0;mi<4;++mi){
        int ar = mw*64 + mi*16 + (lane&15);
        a[mi] = *(const bf16x8*)&As[ar][(kk*4 + (lane>>4))*8];
      }
#pragma unroll
      for (int ni=0;ni<4;++ni){
        int br = nw*64 + ni*16 + (lane&15);
        bf[ni] = *(const bf16x8*)&Bs[br][(kk*4 + (lane>>4))*8];
      }
#pragma unroll
      for (int mi=0;mi<4;++mi)
#pragma unroll
        for (int ni=0;ni<4;++ni)
          acc[mi][ni] = __builtin_amdgcn_mfma_f32_16x16x32_bf16(a[mi], bf[ni], acc[mi][ni], 0, 0, 0);
    }
    __syncthreads();
  }
#pragma unroll
  for (int mi=0;mi<4;++mi){
#pragma unroll
    for (int r=0;r<4;++r){
      int gr = m0 + mw*64 + mi*16 + (lane>>4)*4 + r;
      size_t orow = (size_t)((gr&15)*32 + (gr>>4)) * VX_;
#pragma unroll
      for (int ni=0;ni<4;++ni){
        int col = n0 + nw*64 + ni*16 + (lane&15);
        out[orow + col] = acc[mi][ni][r] + bias[col];
      }
    }
  }
}

// ============ fused softmax + copy-scatter (no final norm; Σfd = 1 analytically) ============
__global__ __launch_bounds__(256) void k_final(float* __restrict__ out, const float* __restrict__ PTR,
    const float* __restrict__ Q, const float* __restrict__ kgo, const float* __restrict__ kpmask,
    const int* __restrict__ kev, const float* __restrict__ KW){
  const int orow = blockIdx.x;
  const int b = orow >> 5, t = orow & 31;
  const int r = t*16 + b;
  const int tid = threadIdx.x;
  float* f = out + (size_t)orow * VX_;
  __shared__ float qs[512];
  __shared__ float part[256];
  __shared__ float red[256];
  __shared__ float valS[512];
  __shared__ int   idxS[512];
  const float ptr = PTR[r];
  qs[tid] = Q[(size_t)r*512 + tid];
  qs[256 + tid] = Q[(size_t)r*512 + 256 + tid];
  __syncthreads();
  for (int k = 0; k < 8; ++k){
    int l = tid >> 2, qtr = tid & 3;
    const float* kgrow = kgo + (size_t)((b*8 + k)*64 + l) * 512;
    float p = 0.f;
    const float4* q4 = (const float4*)(qs) + qtr*32;
    const float4* k4 = (const float4*)(kgrow) + qtr*32;
#pragma unroll 4
    for (int m=0;m<32;++m){ float4 a=q4[m], c=k4[m]; p += a.x*c.x+a.y*c.y+a.z*c.z+a.w*c.w; }
    part[tid] = p;
    __syncthreads();
    if (tid < 64){
      float ev = part[tid*4]+part[tid*4+1]+part[tid*4+2]+part[tid*4+3];
      if (kpmask[(b*8+k)*64 + tid] == 0.f) ev += NEG_;
      float mx = ev;
#pragma unroll
      for (int off=32;off>0;off>>=1) mx = fmaxf(mx, __shfl_xor(mx, off, 64));
      float ex = __expf(ev - mx);
      float z = ex;
#pragma unroll
      for (int off=32;off>0;off>>=1) z += __shfl_xor(z, off, 64);
      valS[k*64 + tid] = (ex/z) * KW[t*128 + b*8 + k] * (1.f - ptr);
      idxS[k*64 + tid] = kev[(b*8+k)*64 + tid];
    }
    __syncthreads();
  }
  float lm = -1e30f;
  for (int v = tid; v < V_; v += 256) lm = fmaxf(lm, f[v]);
  red[tid] = lm; __syncthreads();
  for (int s=128;s>0;s>>=1){ if (tid<s) red[tid]=fmaxf(red[tid],red[tid+s]); __syncthreads(); }
  float M = red[0]; __syncthreads();
  float ls = 0.f;
  for (int v = tid; v < V_; v += 256){ float e2 = __expf(f[v]-M); f[v] = e2; ls += e2; }
  red[tid] = ls; __syncthreads();
  for (int s=128;s>0;s>>=1){ if (tid<s) red[tid]+=red[tid+s]; __syncthreads(); }
  float scale = ptr / red[0];
  for (int v = tid; v < V_; v += 256) f[v] *= scale;
  for (int v = V_ + tid; v < VX_; v += 256) f[v] = 0.f;
  __syncthreads();
  atomicAdd(f + idxS[tid], valS[tid]);
  atomicAdd(f + idxS[256 + tid], valS[256 + tid]);
}

extern "C" void kernel_launch(void* const* d_in, const int* in_sizes, int n_in,
                              void* d_out, int out_size, void* d_ws, size_t ws_size,
                              hipStream_t stream) {
  const int*   tgt   = (const int*)  d_in[0];
  const float* inith = (const float*)d_in[1];
  const float* src   = (const float*)d_in[2];
  const float* smask = (const float*)d_in[3];
  const float* kgh   = (const float*)d_in[4];
  const float* kgf   = (const float*)d_in[5];
  const float* kgo   = (const float*)d_in[6];
  const float* kmask = (const float*)d_in[7];
  const float* kpmask= (const float*)d_in[8];
  const int*   kev   = (const int*)  d_in[10];
  const float* emb   = (const float*)d_in[12];
  const float* W_ih  = (const float*)d_in[13];
  const float* W_hh  = (const float*)d_in[14];
  const float* b_ih  = (const float*)d_in[15];
  const float* b_hh  = (const float*)d_in[16];
  const float* Wq_c  = (const float*)d_in[17];
  const float* Wv_c  = (const float*)d_in[18];
  const float* bv_c  = (const float*)d_in[19];
  const float* Vw_c  = (const float*)d_in[20];
  const float* bV_c  = (const float*)d_in[21];
  const float* Wq_k  = (const float*)d_in[22];
  const float* Wv_k  = (const float*)d_in[23];
  const float* bv_k  = (const float*)d_in[24];
  const float* Vw_k  = (const float*)d_in[25];
  const float* bV_k  = (const float*)d_in[26];
  const float* W1    = (const float*)d_in[27];
  const float* b1    = (const float*)d_in[28];
  const float* W2    = (const float*)d_in[29];
  const float* b2    = (const float*)d_in[30];
  const float* Wptr  = (const float*)d_in[31];
  const float* bptr  = (const float*)d_in[32];
  const float* Wcpy  = (const float*)d_in[33];
  const float* bcpy  = (const float*)d_in[34];
  float* out = (float*)d_out;

  float* Xb    = (float*)d_ws;            // (T,B,1536)
  float* S_all = Xb    + 786432;          // (T*B,512)
  float* PVS   = S_all + 262144;          // (B,S,512)
  float* PVK   = PVS   + 2097152;         // (B,8,512)
  float* KW    = PVK   + 65536;           // (T,B,8)
  float* GIY   = KW    + 4096;            // (T*B,1536)
  float* CK    = GIY   + 786432;          // (16,1024)
  float* HID   = CK    + 16384;           // (512,512)
  float* Qb    = HID   + 262144;          // (512,512)
  float* PTR   = Qb    + 262144;          // (512)
  float* HQC   = PTR   + 512;             // (16,512)
  float* HQK   = HQC   + 8192;            // (16,512)
  float* GH    = HQK   + 8192;            // (16,1536)
  float* Hbuf  = GH    + 24576;           // (16,512)
  float* Eg    = Hbuf  + 8192;            // (16,256)
  unsigned* CNT = (unsigned*)(Eg + 4096); // 128 instances x 288 u32

  hipMemsetAsync(CNT, 0, 128*BARSTRIDE_*sizeof(unsigned), stream);

  // merged prep: embed ∥ PVS ∥ PVK ∥ GIY
  k_prep<<<1384, 256, 0, stream>>>(emb, tgt, src, Wv_c, bv_c, kgh, Wv_k, bv_k, W_ih,
                                   Xb, PVS, PVK, GIY);

  // persistent recurrence: 64 blocks, v4-style phases, tree barrier
  RP7 rp { inith, src, smask, kgh, kmask, Wq_c, Wq_k, Vw_c, bV_c, Vw_k, bV_k,
           W_ih, W_hh, b_ih, b_hh, PVS, PVK, GIY, Xb, S_all, KW,
           HQC, HQK, GH, CK, Hbuf, Eg, CNT };
  k_recur7<<<NBLK_, 512, 0, stream>>>(rp);

  // merged epilogue-1: W1-GEMM(CAT) ∥ Qb-GEMM ∥ ptr
  k_epi<<<192, 256, 0, stream>>>(S_all, Xb, kgf, W1, b1, Wcpy, bcpy, Wptr, bptr, HID, Qb, PTR);
  // bf16 MFMA logits
  k_logits<<<dim3(2,250), 512, 0, stream>>>(HID, W2, b2, out);
  // fused softmax + scatter (no norm)
  k_final<<<512, 256, 0, stream>>>(out, PTR, Qb, kgo, kpmask, kev, KW);
}

// Round 17
// 1753.347 us; speedup vs baseline: 1.5328x; 1.5328x over previous
//
#include <hip/hip_runtime.h>
#include <hip/hip_bf16.h>

#define B_ 16
#define T_ 32
#define S_ 256
#define K_ 8
#define L_ 64
#define V_ 32000
#define VX_ 32050
#define NEG_ -1e10f
#define NBLK_ 128
#define BARSTRIDE_ 288   // 8 groups x 32 u32 + root word

typedef __attribute__((ext_vector_type(8))) __bf16 bf16x8;
typedef __attribute__((ext_vector_type(8))) unsigned short us8;
typedef __attribute__((ext_vector_type(4))) float f32x4;

__device__ __forceinline__ float fsigmoid(float x){ return 1.f/(1.f+__expf(-x)); }
__device__ __forceinline__ float ftanh(float x){ float e=__expf(2.f*x); return 1.f - 2.f/(e+1.f); }
__device__ __forceinline__ unsigned short bf16rne(float f){
  unsigned u = __float_as_uint(f);
  u = u + 0x7FFFu + ((u >> 16) & 1u);
  return (unsigned short)(u >> 16);
}

// ---- LLC-coherent access helpers (device scope via sc0 sc1) ----
__device__ __forceinline__ unsigned ld_llc_u32(const unsigned* p){
  unsigned v;
  asm volatile("global_load_dword %0, %1, off sc0 sc1\n\ts_waitcnt vmcnt(0)" : "=&v"(v) : "v"(p));
  return v;
}
__device__ __forceinline__ float ld_llc_f(const float* p){
  float v;
  asm volatile("global_load_dword %0, %1, off sc0 sc1\n\ts_waitcnt vmcnt(0)" : "=&v"(v) : "v"(p));
  return v;
}
__device__ __forceinline__ f32x4 ld_llc_f4(const float* p){
  f32x4 v;
  asm volatile("global_load_dwordx4 %0, %1, off sc0 sc1\n\ts_waitcnt vmcnt(0)" : "=&v"(v) : "v"(p));
  return v;
}
__device__ __forceinline__ void ld_llc_f4x2(const float* p, f32x4& a, f32x4& b){
  asm volatile("global_load_dwordx4 %0, %2, off sc0 sc1\n\t"
               "global_load_dwordx4 %1, %2, off offset:16 sc0 sc1\n\t"
               "s_waitcnt vmcnt(0)"
               : "=&v"(a), "=&v"(b) : "v"(p));
}
__device__ __forceinline__ void st_llc_f(float* p, float v){
  asm volatile("global_store_dword %0, %1, off sc0 sc1" :: "v"(p), "v"(v) : "memory");
}

// ---- tree barrier: 8 parallel group counters (16 arrivals each) + root (8 arrivals) ----
__device__ __forceinline__ void pbar(unsigned* base, int blk){
  asm volatile("s_waitcnt vmcnt(0)" ::: "memory");
  __syncthreads();
  if (threadIdx.x == 0){
    unsigned* g = base + (blk & 7)*32;
    unsigned* root = base + 256;
    unsigned old = __hip_atomic_fetch_add(g, 1u, __ATOMIC_RELAXED, __HIP_MEMORY_SCOPE_AGENT);
    if (old == 15u)
      __hip_atomic_fetch_add(root, 1u, __ATOMIC_RELAXED, __HIP_MEMORY_SCOPE_AGENT);
    while (ld_llc_u32(root) < 8u) __builtin_amdgcn_s_sleep(1);
  }
  __syncthreads();
}

// ================= merged prep: embed ∥ PVS-GEMM ∥ PVK-GEMM ∥ GIY-GEMM(embed-gather) =================
__global__ __launch_bounds__(256) void k_prep(const float* __restrict__ emb, const int* __restrict__ tgt,
    const float* __restrict__ src, const float* __restrict__ Wv_c, const float* __restrict__ bv_c,
    const float* __restrict__ kgh, const float* __restrict__ Wv_k, const float* __restrict__ bv_k,
    const float* __restrict__ W_ih,
    float* __restrict__ Xb, float* __restrict__ PVS, float* __restrict__ PVK, float* __restrict__ GIY){
  const int bid = blockIdx.x, tid = threadIdx.x;
  if (bid >= 360){   // embed fill: X[t][b][0:512] = emb[tgt[b][t]]
    int idx = (bid-360)*256 + tid;
    int t = idx >> 13; int b = (idx >> 9) & 15; int e = idx & 511;
    int tok = tgt[b*T_ + t];
    Xb[(size_t)(t*B_+b)*1536 + e] = emb[(size_t)tok*512 + e];
    return;
  }
  __shared__ float As[16][132];
  __shared__ float Ws[16][68];
  const float *A, *W, *bias; float* C; int ldA, ldW, ldC, m0, n0; bool gather = false;
  if (bid < 256){      A=src; ldA=512; W=Wv_c; ldW=512; bias=bv_c; C=PVS; ldC=512;
                       m0=(bid&31)*128; n0=(bid>>5)*64; }
  else if (bid < 264){ A=kgh; ldA=512; W=Wv_k; ldW=512; bias=bv_k; C=PVK; ldC=512;
                       m0=0; n0=(bid-256)*64; }
  else {               gather=true; A=nullptr; ldA=0; W=W_ih; ldW=1536; bias=nullptr; C=GIY; ldC=1536;
                       int g=bid-264; m0=(g&3)*128; n0=(g>>2)*64; }
  const int tm = tid & 15, tn = tid >> 4;
  float acc[8][4];
#pragma unroll
  for (int i=0;i<8;++i)
#pragma unroll
    for(int j=0;j<4;++j) acc[i][j]=0.f;
  for (int k0=0;k0<512;k0+=16){
#pragma unroll
    for (int rr=0;rr<2;++rr){
      int f = tid + rr*256;
      int mm = f >> 2, kc = f & 3;
      int m = m0 + mm;
      const float* ap;
      if (gather){
        int tok = tgt[(m & 15)*T_ + (m >> 4)];
        ap = emb + (size_t)tok*512 + k0 + kc*4;
      } else {
        ap = A + (size_t)m*ldA + k0 + kc*4;
      }
      const float4 v = *(const float4*)ap;
      As[kc*4+0][mm]=v.x; As[kc*4+1][mm]=v.y; As[kc*4+2][mm]=v.z; As[kc*4+3][mm]=v.w;
    }
    {
      int nn = tid >> 2, kc = tid & 3;
      const float4 v = *(const float4*)(W + (size_t)(n0+nn)*ldW + k0 + kc*4);
      Ws[kc*4+0][nn]=v.x; Ws[kc*4+1][nn]=v.y; Ws[kc*4+2][nn]=v.z; Ws[kc*4+3][nn]=v.w;
    }
    __syncthreads();
#pragma unroll
    for (int kk=0;kk<16;++kk){
      float a[8], w[4];
      float4 a0 = *(const float4*)&As[kk][tm*8];
      float4 a1 = *(const float4*)&As[kk][tm*8+4];
      float4 w0 = *(const float4*)&Ws[kk][tn*4];
      a[0]=a0.x;a[1]=a0.y;a[2]=a0.z;a[3]=a0.w;a[4]=a1.x;a[5]=a1.y;a[6]=a1.z;a[7]=a1.w;
      w[0]=w0.x;w[1]=w0.y;w[2]=w0.z;w[3]=w0.w;
#pragma unroll
      for (int i=0;i<8;++i)
#pragma unroll
        for (int j=0;j<4;++j) acc[i][j] += a[i]*w[j];
    }
    __syncthreads();
  }
#pragma unroll
  for (int i=0;i<8;++i){
    int m = m0 + tm*8 + i;
#pragma unroll
    for (int j=0;j<4;++j){
      int n = n0 + tn*4 + j;
      C[(size_t)m*ldC + n] = acc[i][j] + (bias ? bias[n] : 0.f);
    }
  }
}

// ================= persistent recurrence: v4 phases (round-10/14, measured best) + tree barrier =================
struct RP4 {
  const float *inith, *src, *smask, *kgh, *kmask;
  const float *Wq_c, *Wq_k, *Vw_c, *bV_c, *Vw_k, *bV_k;
  const float *W_ih, *W_hh, *b_ih, *b_hh;
  const float *PVS, *PVK, *GIY;
  float *Xb, *S_all, *KW;
  float *HQC, *HQK, *GH, *CK, *Hbuf, *Eg;
  unsigned *cnt;
};

__global__ __launch_bounds__(512) void k_recur4(RP4 p){
  __shared__ float SH[4608];
  const int tid = threadIdx.x;
  const int blk = blockIdx.x;
  const float bVc = p.bV_c[0], bVk = p.bV_k[0];

  for (int t = 0; t < T_; ++t){
    // ======== P1: block = (rg 0..31) x (bg 0..3): rows rg*80..+80, batches bg*4..+4 ========
    {
      const int rg = blk & 31, bg = blk >> 5;
      float* hS = SH;   // 4 x 516 = 2064 floats (LDS-safe)
      {
        int i0 = tid*4; int bb = i0 >> 9, cc = i0 & 511;
        float vx,vy,vz,vw;
        if (t == 0){
          float4 v = *(const float4*)(p.inith + (size_t)(bg*4+bb)*512 + cc);
          vx=v.x; vy=v.y; vz=v.z; vw=v.w;
        } else {
          f32x4 v = ld_llc_f4(p.Hbuf + (size_t)(bg*4+bb)*512 + cc);
          vx=v[0]; vy=v[1]; vz=v[2]; vw=v[3];
        }
        hS[bb*516+cc]=vx; hS[bb*516+cc+1]=vy; hS[bb*516+cc+2]=vz; hS[bb*516+cc+3]=vw;
      }
      __syncthreads();
      int rl = tid >> 2, bl = tid & 3;
      if (rl < 80){
        int R = rg*80 + rl;
        const float* wrow = (R < 512) ? (p.Wq_c + (size_t)R*512)
                          : (R < 1024) ? (p.Wq_k + (size_t)(R-512)*512)
                          : (p.W_hh + (size_t)(R-1024)*512);
        const float* hb = hS + bl*516;
        float s = 0.f;
#pragma unroll 8
        for (int m=0;m<128;++m){
          float4 w = *(const float4*)(wrow + m*4);
          float4 hv = *(const float4*)(hb + m*4);
          s += w.x*hv.x + w.y*hv.y + w.z*hv.z + w.w*hv.w;
        }
        int b = bg*4 + bl;
        if (R < 512)       st_llc_f(p.HQC + b*512 + R, s);
        else if (R < 1024) st_llc_f(p.HQK + b*512 + (R-512), s);
        else               st_llc_f(p.GH + b*1536 + (R-1024), s + p.b_hh[R-1024]);
      }
    }
    pbar(p.cnt + (4*t)*BARSTRIDE_, blk);
    __syncthreads();

    // ======== P2: e_src — block = (b 0..15) x (pg 0..7): positions pg*32..+32, 16 thr/row ========
    {
      const int b2 = blk >> 3, pg = blk & 7;
      float* hqcS = SH;        // 16 chunks x 33
      float* vwcS = SH + 528;
      {
        int q = tid >> 5, ii = tid & 31;
        if (tid < 512){
          hqcS[q*33+ii] = ld_llc_f(p.HQC + b2*512 + tid);
          vwcS[q*33+ii] = p.Vw_c[tid];
        }
      }
      __syncthreads();
      int pp = tid >> 4, q = tid & 15;
      int s_i = pg*32 + pp;
      const float4* pv4 = (const float4*)(p.PVS + ((size_t)(b2*S_ + s_i))*512 + q*32);
      const float* hq = hqcS + q*33;
      const float* vw = vwcS + q*33;
      float pe = 0.f;
#pragma unroll
      for (int m=0;m<8;++m){
        float4 v = pv4[m];
        int i0 = m*4;
        pe += ftanh(v.x+hq[i0+0])*vw[i0+0] + ftanh(v.y+hq[i0+1])*vw[i0+1]
            + ftanh(v.z+hq[i0+2])*vw[i0+2] + ftanh(v.w+hq[i0+3])*vw[i0+3];
      }
      pe += __shfl_down(pe, 8, 16);
      pe += __shfl_down(pe, 4, 16);
      pe += __shfl_down(pe, 2, 16);
      pe += __shfl_down(pe, 1, 16);
      if (q == 0){
        float v = pe + bVc;
        if (p.smask[b2*S_ + s_i] == 0.f) v += NEG_;
        st_llc_f(p.Eg + b2*S_ + s_i, v);
      }
    }
    pbar(p.cnt + (4*t+1)*BARSTRIDE_, blk);
    __syncthreads();

    // ======== P3: softmax + c_t/k_t — block = (b 0..15) x (jg 0..7): cols jg*64..+64 ========
    {
      const int b3 = blk >> 3, jg = blk & 7, j0 = jg*64;
      float* eS    = SH;          // 256
      float* wS    = SH + 256;    // 256
      float* hqkS  = SH + 512;    // 64x9 = 576
      float* vwkS  = SH + 1088;   // 576
      float* partS = SH + 1664;   // 512
      float* ekS   = SH + 2176;   // 8
      float* kwS   = SH + 2184;   // 8
      float* MZ    = SH + 2192;   // 2
      if (tid < 64){
        f32x4 v = ld_llc_f4(p.Eg + b3*S_ + tid*4);
        eS[tid*4]=v[0]; eS[tid*4+1]=v[1]; eS[tid*4+2]=v[2]; eS[tid*4+3]=v[3];
      }
      {
        int part = tid >> 3, ii = tid & 7;
        hqkS[part*9+ii] = ld_llc_f(p.HQK + b3*512 + tid);
        vwkS[part*9+ii] = p.Vw_k[tid];
      }
      __syncthreads();
      if (tid < 64){
        float4 e4 = *(const float4*)&eS[tid*4];
        float m = fmaxf(fmaxf(e4.x,e4.y), fmaxf(e4.z,e4.w));
#pragma unroll
        for (int off=32; off>0; off>>=1) m = fmaxf(m, __shfl_xor(m, off, 64));
        float z = __expf(e4.x-m)+__expf(e4.y-m)+__expf(e4.z-m)+__expf(e4.w-m);
#pragma unroll
        for (int off=32; off>0; off>>=1) z += __shfl_xor(z, off, 64);
        if (tid == 0){ MZ[0] = m; MZ[1] = z; }
      }
      {
        int key = tid >> 6, part = tid & 63;
        const float4* pk4 = (const float4*)(p.PVK + ((size_t)(b3*K_ + key))*512 + part*8);
        float4 va = pk4[0], vb = pk4[1];
        const float* hq = hqkS + part*9;
        const float* vw = vwkS + part*9;
        float s2 = ftanh(va.x+hq[0])*vw[0] + ftanh(va.y+hq[1])*vw[1]
                 + ftanh(va.z+hq[2])*vw[2] + ftanh(va.w+hq[3])*vw[3]
                 + ftanh(vb.x+hq[4])*vw[4] + ftanh(vb.y+hq[5])*vw[5]
                 + ftanh(vb.z+hq[6])*vw[6] + ftanh(vb.w+hq[7])*vw[7];
#pragma unroll
        for (int off=32; off>0; off>>=1) s2 += __shfl_xor(s2, off, 64);
        if (part == 0){
          float v = s2 + bVk;
          if (p.kmask[b3*K_ + key] == 0.f) v += NEG_;
          ekS[key] = v;
        }
      }
      __syncthreads();
      if (tid == 0){
        float mk = -1e30f;
#pragma unroll
        for (int k=0;k<8;++k) mk = fmaxf(mk, ekS[k]);
        float z = 0.f; float tmp[8];
#pragma unroll
        for (int k=0;k<8;++k){ tmp[k] = __expf(ekS[k]-mk); z += tmp[k]; }
        float iz = 1.f/z;
#pragma unroll
        for (int k=0;k<8;++k) kwS[k] = tmp[k]*iz;
      }
      __syncthreads();
      float Mv = MZ[0], invZ = 1.f/MZ[1];
      if (tid < 256) wS[tid] = __expf(eS[tid]-Mv);
      __syncthreads();
      {
        int sg = tid >> 6, jl = tid & 63;
        const float* sp = p.src + ((size_t)(b3*S_ + sg*32))*512 + j0 + jl;
        float acc = 0.f;
#pragma unroll 8
        for (int i=0;i<32;++i) acc += wS[sg*32+i] * sp[(size_t)i*512];
        partS[sg*64 + jl] = acc;
      }
      __syncthreads();
      if (tid < 64){
        float c = 0.f;
#pragma unroll
        for (int sg=0; sg<8; ++sg) c += partS[sg*64 + tid];
        c *= invZ;
        float kt = 0.f;
#pragma unroll
        for (int k=0;k<8;++k) kt += kwS[k] * p.kgh[((size_t)(b3*K_+k))*512 + j0 + tid];
        float* Xbt = p.Xb + ((size_t)t*16 + b3)*1536;
        Xbt[512 + j0 + tid]  = c;
        Xbt[1024 + j0 + tid] = kt;
        st_llc_f(p.CK + b3*1024 + j0 + tid, c);
        st_llc_f(p.CK + b3*1024 + 512 + j0 + tid, kt);
      }
      if (jg == 0 && tid < 8) p.KW[t*128 + b3*8 + tid] = kwS[tid];
    }
    pbar(p.cnt + (4*t+2)*BARSTRIDE_, blk);
    __syncthreads();

    // ======== P4: GRU — block = (rg2 0..31) x (bg2 0..3): cols rg2*16..+16, batches bg2*4..+4 ========
    {
      const int rg2 = blk & 31, bg2 = blk >> 5;
      const int j0 = rg2*16, bb0 = bg2*4;
      float* ckS = SH;          // 4 x 1028
      float* giS = SH + 4112;   // 48 x 4
      float* ghS = SH + 4304;   // 48 x 4
      {
        int i0 = tid*8; int bb = i0 >> 10, cc = i0 & 1023;
        f32x4 a, b4;
        ld_llc_f4x2(p.CK + (size_t)(bb0+bb)*1024 + cc, a, b4);
        float* d = ckS + bb*1028 + cc;
        d[0]=a[0]; d[1]=a[1]; d[2]=a[2]; d[3]=a[3];
        d[4]=b4[0]; d[5]=b4[1]; d[6]=b4[2]; d[7]=b4[3];
      }
      __syncthreads();
      int pair = tid >> 1, ks = tid & 1;
      float gi = 0.f;
      int row = 0, bloc = 0, rw = 0;
      if (pair < 192){
        rw = pair >> 2; bloc = pair & 3;
        row = (rw >> 4)*512 + j0 + (rw & 15);
        const float4* wi4 = (const float4*)(p.W_ih + (size_t)row*1536 + 512 + ks*512);
        const float* ckb = ckS + bloc*1028 + ks*512;
#pragma unroll 8
        for (int m=0;m<128;++m){
          float4 w = wi4[m];
          gi += w.x*ckb[m*4] + w.y*ckb[m*4+1] + w.z*ckb[m*4+2] + w.w*ckb[m*4+3];
        }
      }
      gi += __shfl_xor(gi, 1, 64);
      if (pair < 192 && ks == 0){
        int b = bb0 + bloc;
        giS[rw*4 + bloc] = gi + p.GIY[((size_t)t*16 + b)*1536 + row] + p.b_ih[row];
        ghS[rw*4 + bloc] = ld_llc_f(p.GH + b*1536 + row);
      }
      __syncthreads();
      if (tid < 64){
        int jl = tid >> 2, bl2 = tid & 3;
        int b = bb0 + bl2, j = j0 + jl;
        float gir = giS[jl*4+bl2],      giz = giS[(16+jl)*4+bl2],  gin = giS[(32+jl)*4+bl2];
        float ghr = ghS[jl*4+bl2],      ghz = ghS[(16+jl)*4+bl2],  ghn = ghS[(32+jl)*4+bl2];
        float r = fsigmoid(gir + ghr);
        float z = fsigmoid(giz + ghz);
        float n = ftanh(gin + r*ghn);
        float hold = (t == 0) ? p.inith[b*512 + j] : ld_llc_f(p.Hbuf + b*512 + j);
        float hn = (1.f - z)*n + z*hold;
        p.S_all[((size_t)t*16 + b)*512 + j] = hn;
        st_llc_f(p.Hbuf + b*512 + j, hn);
      }
    }
    pbar(p.cnt + (4*t+3)*BARSTRIDE_, blk);
    __syncthreads();
  }
}

// ================= merged epilogue-1: W1-GEMM(CAT-gather) ∥ Qb-GEMM ∥ ptr =================
__global__ __launch_bounds__(256) void k_epi(const float* __restrict__ S_all, const float* __restrict__ X,
    const float* __restrict__ kgf, const float* __restrict__ W1, const float* __restrict__ b1,
    const float* __restrict__ Wcpy, const float* __restrict__ bcpy,
    const float* __restrict__ Wptr, const float* __restrict__ bptr,
    float* __restrict__ HID, float* __restrict__ Qb, float* __restrict__ PTR){
  const int bid = blockIdx.x, tid = threadIdx.x;
  if (bid >= 64){   // ptr: rows (bid-64)*4 .. +4
    int r = (bid-64)*4 + (tid >> 6);
    int lane = tid & 63;
    const float* seg[5];
    seg[0] = X + (size_t)r*1536 + 512;
    seg[1] = S_all + (size_t)r*512;
    seg[2] = X + (size_t)r*1536;
    seg[3] = kgf + (size_t)(r & 15)*512;
    seg[4] = X + (size_t)r*1536 + 1024;
    float s = 0.f;
#pragma unroll
    for (int g=0; g<5; ++g){
      const float* p = seg[g];
      const float* w = Wptr + g*512;
#pragma unroll
      for (int m=0;m<8;++m){ int i = lane + m*64; s += p[i]*w[i]; }
    }
#pragma unroll
    for (int off=32;off>0;off>>=1) s += __shfl_down(s, off, 64);
    if (lane == 0) PTR[r] = fsigmoid(s + bptr[0]);
    return;
  }
  __shared__ float As[16][132];
  __shared__ float Ws[16][68];
  const bool isW1 = (bid < 32);
  const int g = isW1 ? bid : bid-32;
  const int m0 = (g&3)*128, n0 = (g>>2)*64;
  const int KK = isW1 ? 2048 : 512;
  const float* W = isW1 ? W1 : Wcpy;
  const float* bias = isW1 ? b1 : bcpy;
  float* C = isW1 ? HID : Qb;
  const int tm = tid & 15, tn = tid >> 4;
  float acc[8][4];
#pragma unroll
  for (int i=0;i<8;++i)
#pragma unroll
    for(int j=0;j<4;++j) acc[i][j]=0.f;
  for (int k0=0;k0<KK;k0+=16){
#pragma unroll
    for (int rr=0;rr<2;++rr){
      int f = tid + rr*256;
      int mm = f >> 2, kc = f & 3;
      int m = m0 + mm, col = k0 + kc*4;
      const float* ap;
      if (!isW1)            ap = S_all + (size_t)m*512 + col;
      else if (col < 512)   ap = S_all + (size_t)m*512 + col;
      else if (col < 1536)  ap = X + (size_t)m*1536 + col;
      else                  ap = kgf + (size_t)(m & 15)*512 + (col - 1536);
      const float4 v = *(const float4*)ap;
      As[kc*4+0][mm]=v.x; As[kc*4+1][mm]=v.y; As[kc*4+2][mm]=v.z; As[kc*4+3][mm]=v.w;
    }
    {
      int nn = tid >> 2, kc = tid & 3;
      const float4 v = *(const float4*)(W + (size_t)(n0+nn)*KK + k0 + kc*4);
      Ws[kc*4+0][nn]=v.x; Ws[kc*4+1][nn]=v.y; Ws[kc*4+2][nn]=v.z; Ws[kc*4+3][nn]=v.w;
    }
    __syncthreads();
#pragma unroll
    for (int kk=0;kk<16;++kk){
      float a[8], w[4];
      float4 a0 = *(const float4*)&As[kk][tm*8];
      float4 a1 = *(const float4*)&As[kk][tm*8+4];
      float4 w0 = *(const float4*)&Ws[kk][tn*4];
      a[0]=a0.x;a[1]=a0.y;a[2]=a0.z;a[3]=a0.w;a[4]=a1.x;a[5]=a1.y;a[6]=a1.z;a[7]=a1.w;
      w[0]=w0.x;w[1]=w0.y;w[2]=w0.z;w[3]=w0.w;
#pragma unroll
      for (int i=0;i<8;++i)
#pragma unroll
        for (int j=0;j<4;++j) acc[i][j] += a[i]*w[j];
    }
    __syncthreads();
  }
#pragma unroll
  for (int i=0;i<8;++i){
    int m = m0 + tm*8 + i;
#pragma unroll
    for (int j=0;j<4;++j){
      int n = n0 + tn*4 + j;
      C[(size_t)m*512 + n] = acc[i][j] + bias[n];
    }
  }
}

// ============ bf16 MFMA logits GEMM, f32 inputs converted inline (verified) ============
__global__ __launch_bounds__(512) void k_logits(const float* __restrict__ A,
    const float* __restrict__ Bf, const float* __restrict__ bias, float* __restrict__ out){
  __shared__ unsigned short As[256][72];
  __shared__ unsigned short Bs[128][72];
  const int tid = threadIdx.x;
  const int m0 = blockIdx.x*256, n0 = blockIdx.y*128;
  const int lane = tid & 63, wid = tid >> 6;
  const int mw = wid >> 1, nw = wid & 1;
  f32x4 acc[4][4];
#pragma unroll
  for (int i=0;i<4;++i)
#pragma unroll
    for (int j=0;j<4;++j) acc[i][j] = (f32x4){0.f,0.f,0.f,0.f};
  for (int k0 = 0; k0 < 512; k0 += 64){
#pragma unroll
    for (int i=0;i<4;++i){
      int v = i*512 + tid; int row = v >> 3, vc = v & 7;
      const float* srcp = A + (size_t)(m0+row)*512 + k0 + vc*8;
      float4 f0 = *(const float4*)srcp, f1 = *(const float4*)(srcp+4);
      us8 d;
      d[0]=bf16rne(f0.x); d[1]=bf16rne(f0.y); d[2]=bf16rne(f0.z); d[3]=bf16rne(f0.w);
      d[4]=bf16rne(f1.x); d[5]=bf16rne(f1.y); d[6]=bf16rne(f1.z); d[7]=bf16rne(f1.w);
      *(us8*)&As[row][vc*8] = d;
    }
#pragma unroll
    for (int i=0;i<2;++i){
      int v = i*512 + tid; int row = v >> 3, vc = v & 7;
      const float* srcp = Bf + (size_t)(n0+row)*512 + k0 + vc*8;
      float4 f0 = *(const float4*)srcp, f1 = *(const float4*)(srcp+4);
      us8 d;
      d[0]=bf16rne(f0.x); d[1]=bf16rne(f0.y); d[2]=bf16rne(f0.z); d[3]=bf16rne(f0.w);
      d[4]=bf16rne(f1.x); d[5]=bf16rne(f1.y); d[6]=bf16rne(f1.z); d[7]=bf16rne(f1.w);
      *(us8*)&Bs[row][vc*8] = d;
    }
    __syncthreads();
#pragma unroll
    for (int kk=0;kk<2;++kk){
      bf16x8 a[4], bf[4];
#pragma unroll
      for (int mi=0;mi<4;++mi){
        int ar = mw*64 + mi*16 + (lane&15);
        a[mi] = *(const bf16x8*)&As[ar][(kk*4 + (lane>>4))*8];
      }
#pragma unroll
      for (int ni=0;ni<4;++ni){
        int br = nw*64 + ni*16 + (lane&15);
        bf[ni] = *(const bf16x8*)&Bs[br][(kk*4 + (lane>>4))*8];
      }
#pragma unroll
      for (int mi=0;mi<4;++mi)
#pragma unroll
        for (int ni=0;ni<4;++ni)
          acc[mi][ni] = __builtin_amdgcn_mfma_f32_16x16x32_bf16(a[mi], bf[ni], acc[mi][ni], 0, 0, 0);
    }
    __syncthreads();
  }
#pragma unroll
  for (int mi=0;mi<4;++mi){
#pragma unroll
    for (int r=0;r<4;++r){
      int gr = m0 + mw*64 + mi*16 + (lane>>4)*4 + r;
      size_t orow = (size_t)((gr&15)*32 + (gr>>4)) * VX_;
#pragma unroll
      for (int ni=0;ni<4;++ni){
        int col = n0 + nw*64 + ni*16 + (lane&15);
        out[orow + col] = acc[mi][ni][r] + bias[col];
      }
    }
  }
}

// ============ fused softmax + copy-scatter (no final norm; Σfd = 1 analytically) ============
__global__ __launch_bounds__(256) void k_final(float* __restrict__ out, const float* __restrict__ PTR,
    const float* __restrict__ Q, const float* __restrict__ kgo, const float* __restrict__ kpmask,
    const int* __restrict__ kev, const float* __restrict__ KW){
  const int orow = blockIdx.x;
  const int b = orow >> 5, t = orow & 31;
  const int r = t*16 + b;
  const int tid = threadIdx.x;
  float* f = out + (size_t)orow * VX_;
  __shared__ float qs[512];
  __shared__ float part[256];
  __shared__ float red[256];
  __shared__ float valS[512];
  __shared__ int   idxS[512];
  const float ptr = PTR[r];
  qs[tid] = Q[(size_t)r*512 + tid];
  qs[256 + tid] = Q[(size_t)r*512 + 256 + tid];
  __syncthreads();
  for (int k = 0; k < 8; ++k){
    int l = tid >> 2, qtr = tid & 3;
    const float* kgrow = kgo + (size_t)((b*8 + k)*64 + l) * 512;
    float p = 0.f;
    const float4* q4 = (const float4*)(qs) + qtr*32;
    const float4* k4 = (const float4*)(kgrow) + qtr*32;
#pragma unroll 4
    for (int m=0;m<32;++m){ float4 a=q4[m], c=k4[m]; p += a.x*c.x+a.y*c.y+a.z*c.z+a.w*c.w; }
    part[tid] = p;
    __syncthreads();
    if (tid < 64){
      float ev = part[tid*4]+part[tid*4+1]+part[tid*4+2]+part[tid*4+3];
      if (kpmask[(b*8+k)*64 + tid] == 0.f) ev += NEG_;
      float mx = ev;
#pragma unroll
      for (int off=32;off>0;off>>=1) mx = fmaxf(mx, __shfl_xor(mx, off, 64));
      float ex = __expf(ev - mx);
      float z = ex;
#pragma unroll
      for (int off=32;off>0;off>>=1) z += __shfl_xor(z, off, 64);
      valS[k*64 + tid] = (ex/z) * KW[t*128 + b*8 + k] * (1.f - ptr);
      idxS[k*64 + tid] = kev[(b*8+k)*64 + tid];
    }
    __syncthreads();
  }
  float lm = -1e30f;
  for (int v = tid; v < V_; v += 256) lm = fmaxf(lm, f[v]);
  red[tid] = lm; __syncthreads();
  for (int s=128;s>0;s>>=1){ if (tid<s) red[tid]=fmaxf(red[tid],red[tid+s]); __syncthreads(); }
  float M = red[0]; __syncthreads();
  float ls = 0.f;
  for (int v = tid; v < V_; v += 256){ float e2 = __expf(f[v]-M); f[v] = e2; ls += e2; }
  red[tid] = ls; __syncthreads();
  for (int s=128;s>0;s>>=1){ if (tid<s) red[tid]+=red[tid+s]; __syncthreads(); }
  float scale = ptr / red[0];
  for (int v = tid; v < V_; v += 256) f[v] *= scale;
  for (int v = V_ + tid; v < VX_; v += 256) f[v] = 0.f;
  __syncthreads();
  atomicAdd(f + idxS[tid], valS[tid]);
  atomicAdd(f + idxS[256 + tid], valS[256 + tid]);
}

extern "C" void kernel_launch(void* const* d_in, const int* in_sizes, int n_in,
                              void* d_out, int out_size, void* d_ws, size_t ws_size,
                              hipStream_t stream) {
  const int*   tgt   = (const int*)  d_in[0];
  const float* inith = (const float*)d_in[1];
  const float* src   = (const float*)d_in[2];
  const float* smask = (const float*)d_in[3];
  const float* kgh   = (const float*)d_in[4];
  const float* kgf   = (const float*)d_in[5];
  const float* kgo   = (const float*)d_in[6];
  const float* kmask = (const float*)d_in[7];
  const float* kpmask= (const float*)d_in[8];
  const int*   kev   = (const int*)  d_in[10];
  const float* emb   = (const float*)d_in[12];
  const float* W_ih  = (const float*)d_in[13];
  const float* W_hh  = (const float*)d_in[14];
  const float* b_ih  = (const float*)d_in[15];
  const float* b_hh  = (const float*)d_in[16];
  const float* Wq_c  = (const float*)d_in[17];
  const float* Wv_c  = (const float*)d_in[18];
  const float* bv_c  = (const float*)d_in[19];
  const float* Vw_c  = (const float*)d_in[20];
  const float* bV_c  = (const float*)d_in[21];
  const float* Wq_k  = (const float*)d_in[22];
  const float* Wv_k  = (const float*)d_in[23];
  const float* bv_k  = (const float*)d_in[24];
  const float* Vw_k  = (const float*)d_in[25];
  const float* bV_k  = (const float*)d_in[26];
  const float* W1    = (const float*)d_in[27];
  const float* b1    = (const float*)d_in[28];
  const float* W2    = (const float*)d_in[29];
  const float* b2    = (const float*)d_in[30];
  const float* Wptr  = (const float*)d_in[31];
  const float* bptr  = (const float*)d_in[32];
  const float* Wcpy  = (const float*)d_in[33];
  const float* bcpy  = (const float*)d_in[34];
  float* out = (float*)d_out;

  float* Xb    = (float*)d_ws;            // (T,B,1536)
  float* S_all = Xb    + 786432;          // (T*B,512)
  float* PVS   = S_all + 262144;          // (B,S,512)
  float* PVK   = PVS   + 2097152;         // (B,8,512)
  float* KW    = PVK   + 65536;           // (T,B,8)
  float* GIY   = KW    + 4096;            // (T*B,1536)
  float* CK    = GIY   + 786432;          // (16,1024)
  float* HID   = CK    + 16384;           // (512,512)
  float* Qb    = HID   + 262144;          // (512,512)
  float* PTR   = Qb    + 262144;          // (512)
  float* HQC   = PTR   + 512;             // (16,512)
  float* HQK   = HQC   + 8192;            // (16,512)
  float* GH    = HQK   + 8192;            // (16,1536)
  float* Hbuf  = GH    + 24576;           // (16,512)
  float* Eg    = Hbuf  + 8192;            // (16,256)
  unsigned* CNT = (unsigned*)(Eg + 4096); // 128 instances x 288 u32

  hipMemsetAsync(CNT, 0, 128*BARSTRIDE_*sizeof(unsigned), stream);

  // merged prep: embed ∥ PVS ∥ PVK ∥ GIY
  k_prep<<<1384, 256, 0, stream>>>(emb, tgt, src, Wv_c, bv_c, kgh, Wv_k, bv_k, W_ih,
                                   Xb, PVS, PVK, GIY);

  // persistent recurrence: v4 phases + tree barrier (measured-best configuration)
  RP4 rp { inith, src, smask, kgh, kmask, Wq_c, Wq_k, Vw_c, bV_c, Vw_k, bV_k,
           W_ih, W_hh, b_ih, b_hh, PVS, PVK, GIY, Xb, S_all, KW,
           HQC, HQK, GH, CK, Hbuf, Eg, CNT };
  k_recur4<<<NBLK_, 512, 0, stream>>>(rp);

  // merged epilogue-1: W1-GEMM(CAT) ∥ Qb-GEMM ∥ ptr
  k_epi<<<192, 256, 0, stream>>>(S_all, Xb, kgf, W1, b1, Wcpy, bcpy, Wptr, bptr, HID, Qb, PTR);
  // bf16 MFMA logits
  k_logits<<<dim3(2,250), 512, 0, stream>>>(HID, W2, b2, out);
  // fused softmax + scatter (no norm)
  k_final<<<512, 256, 0, stream>>>(out, PTR, Qb, kgo, kpmask, kev, KW);
}

// Round 18
// 1683.368 us; speedup vs baseline: 1.5965x; 1.0416x over previous
//
#include <hip/hip_runtime.h>
#include <hip/hip_bf16.h>

#define B_ 16
#define T_ 32
#define S_ 256
#define K_ 8
#define L_ 64
#define V_ 32000
#define VX_ 32050
#define NEG_ -1e10f
#define NBLK_ 128
#define BARSTRIDE_ 288   // 8 leaf stripes x 32 u32 (counter + flag line) + root word

typedef __attribute__((ext_vector_type(8))) __bf16 bf16x8;
typedef __attribute__((ext_vector_type(8))) unsigned short us8;
typedef __attribute__((ext_vector_type(4))) float f32x4;

__device__ __forceinline__ float fsigmoid(float x){ return 1.f/(1.f+__expf(-x)); }
__device__ __forceinline__ float ftanh(float x){ float e=__expf(2.f*x); return 1.f - 2.f/(e+1.f); }
__device__ __forceinline__ unsigned short bf16rne(float f){
  unsigned u = __float_as_uint(f);
  u = u + 0x7FFFu + ((u >> 16) & 1u);
  return (unsigned short)(u >> 16);
}

// ---- LLC-coherent access helpers (device scope via sc0 sc1) ----
__device__ __forceinline__ unsigned ld_llc_u32(const unsigned* p){
  unsigned v;
  asm volatile("global_load_dword %0, %1, off sc0 sc1\n\ts_waitcnt vmcnt(0)" : "=&v"(v) : "v"(p));
  return v;
}
__device__ __forceinline__ void st_llc_u32(unsigned* p, unsigned v){
  asm volatile("global_store_dword %0, %1, off sc0 sc1" :: "v"(p), "v"(v) : "memory");
}
__device__ __forceinline__ float ld_llc_f(const float* p){
  float v;
  asm volatile("global_load_dword %0, %1, off sc0 sc1\n\ts_waitcnt vmcnt(0)" : "=&v"(v) : "v"(p));
  return v;
}
__device__ __forceinline__ f32x4 ld_llc_f4(const float* p){
  f32x4 v;
  asm volatile("global_load_dwordx4 %0, %1, off sc0 sc1\n\ts_waitcnt vmcnt(0)" : "=&v"(v) : "v"(p));
  return v;
}
__device__ __forceinline__ void ld_llc_f4x2(const float* p, f32x4& a, f32x4& b){
  asm volatile("global_load_dwordx4 %0, %2, off sc0 sc1\n\t"
               "global_load_dwordx4 %1, %2, off offset:16 sc0 sc1\n\t"
               "s_waitcnt vmcnt(0)"
               : "=&v"(a), "=&v"(b) : "v"(p));
}
__device__ __forceinline__ void st_llc_f(float* p, float v){
  asm volatile("global_store_dword %0, %1, off sc0 sc1" :: "v"(p), "v"(v) : "memory");
}

// ---- hierarchical-release tree barrier: leaf count (16) -> root count (8) -> per-group flag ----
// Pollers never touch the arrival lines: <=15 blocks poll each group flag; only 8 leaf-finishers
// poll the root. Eliminates poller/arrival same-line contention.
__device__ __forceinline__ void pbar(unsigned* base, int blk){
  asm volatile("s_waitcnt vmcnt(0)" ::: "memory");
  __syncthreads();
  if (threadIdx.x == 0){
    unsigned* leaf  = base + (blk & 7)*32;   // own 64B line
    unsigned* gflag = leaf + 16;             // next 64B line within the stripe
    unsigned* root  = base + 256;            // own line
    unsigned old = __hip_atomic_fetch_add(leaf, 1u, __ATOMIC_RELAXED, __HIP_MEMORY_SCOPE_AGENT);
    if (old == 15u){
      __hip_atomic_fetch_add(root, 1u, __ATOMIC_RELAXED, __HIP_MEMORY_SCOPE_AGENT);
      while (ld_llc_u32(root) < 8u) __builtin_amdgcn_s_sleep(2);
      st_llc_u32(gflag, 1u);
    } else {
      while (ld_llc_u32(gflag) == 0u) __builtin_amdgcn_s_sleep(2);
    }
  }
  __syncthreads();
}

// ================= merged prep: embed ∥ PVS-GEMM ∥ PVK-GEMM ∥ GIY-GEMM(embed-gather) =================
__global__ __launch_bounds__(256) void k_prep(const float* __restrict__ emb, const int* __restrict__ tgt,
    const float* __restrict__ src, const float* __restrict__ Wv_c, const float* __restrict__ bv_c,
    const float* __restrict__ kgh, const float* __restrict__ Wv_k, const float* __restrict__ bv_k,
    const float* __restrict__ W_ih,
    float* __restrict__ Xb, float* __restrict__ PVS, float* __restrict__ PVK, float* __restrict__ GIY){
  const int bid = blockIdx.x, tid = threadIdx.x;
  if (bid >= 360){   // embed fill: X[t][b][0:512] = emb[tgt[b][t]]
    int idx = (bid-360)*256 + tid;
    int t = idx >> 13; int b = (idx >> 9) & 15; int e = idx & 511;
    int tok = tgt[b*T_ + t];
    Xb[(size_t)(t*B_+b)*1536 + e] = emb[(size_t)tok*512 + e];
    return;
  }
  __shared__ float As[16][132];
  __shared__ float Ws[16][68];
  const float *A, *W, *bias; float* C; int ldA, ldW, ldC, m0, n0; bool gather = false;
  if (bid < 256){      A=src; ldA=512; W=Wv_c; ldW=512; bias=bv_c; C=PVS; ldC=512;
                       m0=(bid&31)*128; n0=(bid>>5)*64; }
  else if (bid < 264){ A=kgh; ldA=512; W=Wv_k; ldW=512; bias=bv_k; C=PVK; ldC=512;
                       m0=0; n0=(bid-256)*64; }
  else {               gather=true; A=nullptr; ldA=0; W=W_ih; ldW=1536; bias=nullptr; C=GIY; ldC=1536;
                       int g=bid-264; m0=(g&3)*128; n0=(g>>2)*64; }
  const int tm = tid & 15, tn = tid >> 4;
  float acc[8][4];
#pragma unroll
  for (int i=0;i<8;++i)
#pragma unroll
    for(int j=0;j<4;++j) acc[i][j]=0.f;
  for (int k0=0;k0<512;k0+=16){
#pragma unroll
    for (int rr=0;rr<2;++rr){
      int f = tid + rr*256;
      int mm = f >> 2, kc = f & 3;
      int m = m0 + mm;
      const float* ap;
      if (gather){
        int tok = tgt[(m & 15)*T_ + (m >> 4)];
        ap = emb + (size_t)tok*512 + k0 + kc*4;
      } else {
        ap = A + (size_t)m*ldA + k0 + kc*4;
      }
      const float4 v = *(const float4*)ap;
      As[kc*4+0][mm]=v.x; As[kc*4+1][mm]=v.y; As[kc*4+2][mm]=v.z; As[kc*4+3][mm]=v.w;
    }
    {
      int nn = tid >> 2, kc = tid & 3;
      const float4 v = *(const float4*)(W + (size_t)(n0+nn)*ldW + k0 + kc*4);
      Ws[kc*4+0][nn]=v.x; Ws[kc*4+1][nn]=v.y; Ws[kc*4+2][nn]=v.z; Ws[kc*4+3][nn]=v.w;
    }
    __syncthreads();
#pragma unroll
    for (int kk=0;kk<16;++kk){
      float a[8], w[4];
      float4 a0 = *(const float4*)&As[kk][tm*8];
      float4 a1 = *(const float4*)&As[kk][tm*8+4];
      float4 w0 = *(const float4*)&Ws[kk][tn*4];
      a[0]=a0.x;a[1]=a0.y;a[2]=a0.z;a[3]=a0.w;a[4]=a1.x;a[5]=a1.y;a[6]=a1.z;a[7]=a1.w;
      w[0]=w0.x;w[1]=w0.y;w[2]=w0.z;w[3]=w0.w;
#pragma unroll
      for (int i=0;i<8;++i)
#pragma unroll
        for (int j=0;j<4;++j) acc[i][j] += a[i]*w[j];
    }
    __syncthreads();
  }
#pragma unroll
  for (int i=0;i<8;++i){
    int m = m0 + tm*8 + i;
#pragma unroll
    for (int j=0;j<4;++j){
      int n = n0 + tn*4 + j;
      C[(size_t)m*ldC + n] = acc[i][j] + (bias ? bias[n] : 0.f);
    }
  }
}

// ================= persistent recurrence: v4 phases (measured best) + hierarchical barrier =================
struct RP4 {
  const float *inith, *src, *smask, *kgh, *kmask;
  const float *Wq_c, *Wq_k, *Vw_c, *bV_c, *Vw_k, *bV_k;
  const float *W_ih, *W_hh, *b_ih, *b_hh;
  const float *PVS, *PVK, *GIY;
  float *Xb, *S_all, *KW;
  float *HQC, *HQK, *GH, *CK, *Hbuf, *Eg;
  unsigned *cnt;
};

__global__ __launch_bounds__(512) void k_recur4(RP4 p){
  __shared__ float SH[4608];
  const int tid = threadIdx.x;
  const int blk = blockIdx.x;
  const float bVc = p.bV_c[0], bVk = p.bV_k[0];

  for (int t = 0; t < T_; ++t){
    // ======== P1: block = (rg 0..31) x (bg 0..3): rows rg*80..+80, batches bg*4..+4 ========
    {
      const int rg = blk & 31, bg = blk >> 5;
      float* hS = SH;   // 4 x 516 = 2064 floats (LDS-safe)
      {
        int i0 = tid*4; int bb = i0 >> 9, cc = i0 & 511;
        float vx,vy,vz,vw;
        if (t == 0){
          float4 v = *(const float4*)(p.inith + (size_t)(bg*4+bb)*512 + cc);
          vx=v.x; vy=v.y; vz=v.z; vw=v.w;
        } else {
          f32x4 v = ld_llc_f4(p.Hbuf + (size_t)(bg*4+bb)*512 + cc);
          vx=v[0]; vy=v[1]; vz=v[2]; vw=v[3];
        }
        hS[bb*516+cc]=vx; hS[bb*516+cc+1]=vy; hS[bb*516+cc+2]=vz; hS[bb*516+cc+3]=vw;
      }
      __syncthreads();
      int rl = tid >> 2, bl = tid & 3;
      if (rl < 80){
        int R = rg*80 + rl;
        const float* wrow = (R < 512) ? (p.Wq_c + (size_t)R*512)
                          : (R < 1024) ? (p.Wq_k + (size_t)(R-512)*512)
                          : (p.W_hh + (size_t)(R-1024)*512);
        const float* hb = hS + bl*516;
        float s = 0.f;
#pragma unroll 8
        for (int m=0;m<128;++m){
          float4 w = *(const float4*)(wrow + m*4);
          float4 hv = *(const float4*)(hb + m*4);
          s += w.x*hv.x + w.y*hv.y + w.z*hv.z + w.w*hv.w;
        }
        int b = bg*4 + bl;
        if (R < 512)       st_llc_f(p.HQC + b*512 + R, s);
        else if (R < 1024) st_llc_f(p.HQK + b*512 + (R-512), s);
        else               st_llc_f(p.GH + b*1536 + (R-1024), s + p.b_hh[R-1024]);
      }
    }
    pbar(p.cnt + (4*t)*BARSTRIDE_, blk);
    __syncthreads();

    // ======== P2: e_src — block = (b 0..15) x (pg 0..7): positions pg*32..+32, 16 thr/row ========
    {
      const int b2 = blk >> 3, pg = blk & 7;
      float* hqcS = SH;        // 16 chunks x 33
      float* vwcS = SH + 528;
      {
        int q = tid >> 5, ii = tid & 31;
        if (tid < 512){
          hqcS[q*33+ii] = ld_llc_f(p.HQC + b2*512 + tid);
          vwcS[q*33+ii] = p.Vw_c[tid];
        }
      }
      __syncthreads();
      int pp = tid >> 4, q = tid & 15;
      int s_i = pg*32 + pp;
      const float4* pv4 = (const float4*)(p.PVS + ((size_t)(b2*S_ + s_i))*512 + q*32);
      const float* hq = hqcS + q*33;
      const float* vw = vwcS + q*33;
      float pe = 0.f;
#pragma unroll
      for (int m=0;m<8;++m){
        float4 v = pv4[m];
        int i0 = m*4;
        pe += ftanh(v.x+hq[i0+0])*vw[i0+0] + ftanh(v.y+hq[i0+1])*vw[i0+1]
            + ftanh(v.z+hq[i0+2])*vw[i0+2] + ftanh(v.w+hq[i0+3])*vw[i0+3];
      }
      pe += __shfl_down(pe, 8, 16);
      pe += __shfl_down(pe, 4, 16);
      pe += __shfl_down(pe, 2, 16);
      pe += __shfl_down(pe, 1, 16);
      if (q == 0){
        float v = pe + bVc;
        if (p.smask[b2*S_ + s_i] == 0.f) v += NEG_;
        st_llc_f(p.Eg + b2*S_ + s_i, v);
      }
    }
    pbar(p.cnt + (4*t+1)*BARSTRIDE_, blk);
    __syncthreads();

    // ======== P3: softmax + c_t/k_t — block = (b 0..15) x (jg 0..7): cols jg*64..+64 ========
    {
      const int b3 = blk >> 3, jg = blk & 7, j0 = jg*64;
      float* eS    = SH;          // 256
      float* wS    = SH + 256;    // 256
      float* hqkS  = SH + 512;    // 64x9 = 576
      float* vwkS  = SH + 1088;   // 576
      float* partS = SH + 1664;   // 512
      float* ekS   = SH + 2176;   // 8
      float* kwS   = SH + 2184;   // 8
      float* MZ    = SH + 2192;   // 2
      if (tid < 64){
        f32x4 v = ld_llc_f4(p.Eg + b3*S_ + tid*4);
        eS[tid*4]=v[0]; eS[tid*4+1]=v[1]; eS[tid*4+2]=v[2]; eS[tid*4+3]=v[3];
      }
      {
        int part = tid >> 3, ii = tid & 7;
        hqkS[part*9+ii] = ld_llc_f(p.HQK + b3*512 + tid);
        vwkS[part*9+ii] = p.Vw_k[tid];
      }
      __syncthreads();
      if (tid < 64){
        float4 e4 = *(const float4*)&eS[tid*4];
        float m = fmaxf(fmaxf(e4.x,e4.y), fmaxf(e4.z,e4.w));
#pragma unroll
        for (int off=32; off>0; off>>=1) m = fmaxf(m, __shfl_xor(m, off, 64));
        float z = __expf(e4.x-m)+__expf(e4.y-m)+__expf(e4.z-m)+__expf(e4.w-m);
#pragma unroll
        for (int off=32; off>0; off>>=1) z += __shfl_xor(z, off, 64);
        if (tid == 0){ MZ[0] = m; MZ[1] = z; }
      }
      {
        int key = tid >> 6, part = tid & 63;
        const float4* pk4 = (const float4*)(p.PVK + ((size_t)(b3*K_ + key))*512 + part*8);
        float4 va = pk4[0], vb = pk4[1];
        const float* hq = hqkS + part*9;
        const float* vw = vwkS + part*9;
        float s2 = ftanh(va.x+hq[0])*vw[0] + ftanh(va.y+hq[1])*vw[1]
                 + ftanh(va.z+hq[2])*vw[2] + ftanh(va.w+hq[3])*vw[3]
                 + ftanh(vb.x+hq[4])*vw[4] + ftanh(vb.y+hq[5])*vw[5]
                 + ftanh(vb.z+hq[6])*vw[6] + ftanh(vb.w+hq[7])*vw[7];
#pragma unroll
        for (int off=32; off>0; off>>=1) s2 += __shfl_xor(s2, off, 64);
        if (part == 0){
          float v = s2 + bVk;
          if (p.kmask[b3*K_ + key] == 0.f) v += NEG_;
          ekS[key] = v;
        }
      }
      __syncthreads();
      if (tid == 0){
        float mk = -1e30f;
#pragma unroll
        for (int k=0;k<8;++k) mk = fmaxf(mk, ekS[k]);
        float z = 0.f; float tmp[8];
#pragma unroll
        for (int k=0;k<8;++k){ tmp[k] = __expf(ekS[k]-mk); z += tmp[k]; }
        float iz = 1.f/z;
#pragma unroll
        for (int k=0;k<8;++k) kwS[k] = tmp[k]*iz;
      }
      __syncthreads();
      float Mv = MZ[0], invZ = 1.f/MZ[1];
      if (tid < 256) wS[tid] = __expf(eS[tid]-Mv);
      __syncthreads();
      {
        int sg = tid >> 6, jl = tid & 63;
        const float* sp = p.src + ((size_t)(b3*S_ + sg*32))*512 + j0 + jl;
        float acc = 0.f;
#pragma unroll 8
        for (int i=0;i<32;++i) acc += wS[sg*32+i] * sp[(size_t)i*512];
        partS[sg*64 + jl] = acc;
      }
      __syncthreads();
      if (tid < 64){
        float c = 0.f;
#pragma unroll
        for (int sg=0; sg<8; ++sg) c += partS[sg*64 + tid];
        c *= invZ;
        float kt = 0.f;
#pragma unroll
        for (int k=0;k<8;++k) kt += kwS[k] * p.kgh[((size_t)(b3*K_+k))*512 + j0 + tid];
        float* Xbt = p.Xb + ((size_t)t*16 + b3)*1536;
        Xbt[512 + j0 + tid]  = c;
        Xbt[1024 + j0 + tid] = kt;
        st_llc_f(p.CK + b3*1024 + j0 + tid, c);
        st_llc_f(p.CK + b3*1024 + 512 + j0 + tid, kt);
      }
      if (jg == 0 && tid < 8) p.KW[t*128 + b3*8 + tid] = kwS[tid];
    }
    pbar(p.cnt + (4*t+2)*BARSTRIDE_, blk);
    __syncthreads();

    // ======== P4: GRU — block = (rg2 0..31) x (bg2 0..3): cols rg2*16..+16, batches bg2*4..+4 ========
    {
      const int rg2 = blk & 31, bg2 = blk >> 5;
      const int j0 = rg2*16, bb0 = bg2*4;
      float* ckS = SH;          // 4 x 1028
      float* giS = SH + 4112;   // 48 x 4
      float* ghS = SH + 4304;   // 48 x 4
      {
        int i0 = tid*8; int bb = i0 >> 10, cc = i0 & 1023;
        f32x4 a, b4;
        ld_llc_f4x2(p.CK + (size_t)(bb0+bb)*1024 + cc, a, b4);
        float* d = ckS + bb*1028 + cc;
        d[0]=a[0]; d[1]=a[1]; d[2]=a[2]; d[3]=a[3];
        d[4]=b4[0]; d[5]=b4[1]; d[6]=b4[2]; d[7]=b4[3];
      }
      __syncthreads();
      int pair = tid >> 1, ks = tid & 1;
      float gi = 0.f;
      int row = 0, bloc = 0, rw = 0;
      if (pair < 192){
        rw = pair >> 2; bloc = pair & 3;
        row = (rw >> 4)*512 + j0 + (rw & 15);
        const float4* wi4 = (const float4*)(p.W_ih + (size_t)row*1536 + 512 + ks*512);
        const float* ckb = ckS + bloc*1028 + ks*512;
#pragma unroll 8
        for (int m=0;m<128;++m){
          float4 w = wi4[m];
          gi += w.x*ckb[m*4] + w.y*ckb[m*4+1] + w.z*ckb[m*4+2] + w.w*ckb[m*4+3];
        }
      }
      gi += __shfl_xor(gi, 1, 64);
      if (pair < 192 && ks == 0){
        int b = bb0 + bloc;
        giS[rw*4 + bloc] = gi + p.GIY[((size_t)t*16 + b)*1536 + row] + p.b_ih[row];
        ghS[rw*4 + bloc] = ld_llc_f(p.GH + b*1536 + row);
      }
      __syncthreads();
      if (tid < 64){
        int jl = tid >> 2, bl2 = tid & 3;
        int b = bb0 + bl2, j = j0 + jl;
        float gir = giS[jl*4+bl2],      giz = giS[(16+jl)*4+bl2],  gin = giS[(32+jl)*4+bl2];
        float ghr = ghS[jl*4+bl2],      ghz = ghS[(16+jl)*4+bl2],  ghn = ghS[(32+jl)*4+bl2];
        float r = fsigmoid(gir + ghr);
        float z = fsigmoid(giz + ghz);
        float n = ftanh(gin + r*ghn);
        float hold = (t == 0) ? p.inith[b*512 + j] : ld_llc_f(p.Hbuf + b*512 + j);
        float hn = (1.f - z)*n + z*hold;
        p.S_all[((size_t)t*16 + b)*512 + j] = hn;
        st_llc_f(p.Hbuf + b*512 + j, hn);
      }
    }
    pbar(p.cnt + (4*t+3)*BARSTRIDE_, blk);
    __syncthreads();
  }
}

// ================= merged epilogue-1: W1-GEMM(CAT-gather) ∥ Qb-GEMM ∥ ptr =================
__global__ __launch_bounds__(256) void k_epi(const float* __restrict__ S_all, const float* __restrict__ X,
    const float* __restrict__ kgf, const float* __restrict__ W1, const float* __restrict__ b1,
    const float* __restrict__ Wcpy, const float* __restrict__ bcpy,
    const float* __restrict__ Wptr, const float* __restrict__ bptr,
    float* __restrict__ HID, float* __restrict__ Qb, float* __restrict__ PTR){
  const int bid = blockIdx.x, tid = threadIdx.x;
  if (bid >= 64){   // ptr: rows (bid-64)*4 .. +4
    int r = (bid-64)*4 + (tid >> 6);
    int lane = tid & 63;
    const float* seg[5];
    seg[0] = X + (size_t)r*1536 + 512;
    seg[1] = S_all + (size_t)r*512;
    seg[2] = X + (size_t)r*1536;
    seg[3] = kgf + (size_t)(r & 15)*512;
    seg[4] = X + (size_t)r*1536 + 1024;
    float s = 0.f;
#pragma unroll
    for (int g=0; g<5; ++g){
      const float* p = seg[g];
      const float* w = Wptr + g*512;
#pragma unroll
      for (int m=0;m<8;++m){ int i = lane + m*64; s += p[i]*w[i]; }
    }
#pragma unroll
    for (int off=32;off>0;off>>=1) s += __shfl_down(s, off, 64);
    if (lane == 0) PTR[r] = fsigmoid(s + bptr[0]);
    return;
  }
  __shared__ float As[16][132];
  __shared__ float Ws[16][68];
  const bool isW1 = (bid < 32);
  const int g = isW1 ? bid : bid-32;
  const int m0 = (g&3)*128, n0 = (g>>2)*64;
  const int KK = isW1 ? 2048 : 512;
  const float* W = isW1 ? W1 : Wcpy;
  const float* bias = isW1 ? b1 : bcpy;
  float* C = isW1 ? HID : Qb;
  const int tm = tid & 15, tn = tid >> 4;
  float acc[8][4];
#pragma unroll
  for (int i=0;i<8;++i)
#pragma unroll
    for(int j=0;j<4;++j) acc[i][j]=0.f;
  for (int k0=0;k0<KK;k0+=16){
#pragma unroll
    for (int rr=0;rr<2;++rr){
      int f = tid + rr*256;
      int mm = f >> 2, kc = f & 3;
      int m = m0 + mm, col = k0 + kc*4;
      const float* ap;
      if (!isW1)            ap = S_all + (size_t)m*512 + col;
      else if (col < 512)   ap = S_all + (size_t)m*512 + col;
      else if (col < 1536)  ap = X + (size_t)m*1536 + col;
      else                  ap = kgf + (size_t)(m & 15)*512 + (col - 1536);
      const float4 v = *(const float4*)ap;
      As[kc*4+0][mm]=v.x; As[kc*4+1][mm]=v.y; As[kc*4+2][mm]=v.z; As[kc*4+3][mm]=v.w;
    }
    {
      int nn = tid >> 2, kc = tid & 3;
      const float4 v = *(const float4*)(W + (size_t)(n0+nn)*KK + k0 + kc*4);
      Ws[kc*4+0][nn]=v.x; Ws[kc*4+1][nn]=v.y; Ws[kc*4+2][nn]=v.z; Ws[kc*4+3][nn]=v.w;
    }
    __syncthreads();
#pragma unroll
    for (int kk=0;kk<16;++kk){
      float a[8], w[4];
      float4 a0 = *(const float4*)&As[kk][tm*8];
      float4 a1 = *(const float4*)&As[kk][tm*8+4];
      float4 w0 = *(const float4*)&Ws[kk][tn*4];
      a[0]=a0.x;a[1]=a0.y;a[2]=a0.z;a[3]=a0.w;a[4]=a1.x;a[5]=a1.y;a[6]=a1.z;a[7]=a1.w;
      w[0]=w0.x;w[1]=w0.y;w[2]=w0.z;w[3]=w0.w;
#pragma unroll
      for (int i=0;i<8;++i)
#pragma unroll
        for (int j=0;j<4;++j) acc[i][j] += a[i]*w[j];
    }
    __syncthreads();
  }
#pragma unroll
  for (int i=0;i<8;++i){
    int m = m0 + tm*8 + i;
#pragma unroll
    for (int j=0;j<4;++j){
      int n = n0 + tn*4 + j;
      C[(size_t)m*512 + n] = acc[i][j] + bias[n];
    }
  }
}

// ============ bf16 MFMA logits GEMM, f32 inputs converted inline (verified) ============
__global__ __launch_bounds__(512) void k_logits(const float* __restrict__ A,
    const float* __restrict__ Bf, const float* __restrict__ bias, float* __restrict__ out){
  __shared__ unsigned short As[256][72];
  __shared__ unsigned short Bs[128][72];
  const int tid = threadIdx.x;
  const int m0 = blockIdx.x*256, n0 = blockIdx.y*128;
  const int lane = tid & 63, wid = tid >> 6;
  const int mw = wid >> 1, nw = wid & 1;
  f32x4 acc[4][4];
#pragma unroll
  for (int i=0;i<4;++i)
#pragma unroll
    for (int j=0;j<4;++j) acc[i][j] = (f32x4){0.f,0.f,0.f,0.f};
  for (int k0 = 0; k0 < 512; k0 += 64){
#pragma unroll
    for (int i=0;i<4;++i){
      int v = i*512 + tid; int row = v >> 3, vc = v & 7;
      const float* srcp = A + (size_t)(m0+row)*512 + k0 + vc*8;
      float4 f0 = *(const float4*)srcp, f1 = *(const float4*)(srcp+4);
      us8 d;
      d[0]=bf16rne(f0.x); d[1]=bf16rne(f0.y); d[2]=bf16rne(f0.z); d[3]=bf16rne(f0.w);
      d[4]=bf16rne(f1.x); d[5]=bf16rne(f1.y); d[6]=bf16rne(f1.z); d[7]=bf16rne(f1.w);
      *(us8*)&As[row][vc*8] = d;
    }
#pragma unroll
    for (int i=0;i<2;++i){
      int v = i*512 + tid; int row = v >> 3, vc = v & 7;
      const float* srcp = Bf + (size_t)(n0+row)*512 + k0 + vc*8;
      float4 f0 = *(const float4*)srcp, f1 = *(const float4*)(srcp+4);
      us8 d;
      d[0]=bf16rne(f0.x); d[1]=bf16rne(f0.y); d[2]=bf16rne(f0.z); d[3]=bf16rne(f0.w);
      d[4]=bf16rne(f1.x); d[5]=bf16rne(f1.y); d[6]=bf16rne(f1.z); d[7]=bf16rne(f1.w);
      *(us8*)&Bs[row][vc*8] = d;
    }
    __syncthreads();
#pragma unroll
    for (int kk=0;kk<2;++kk){
      bf16x8 a[4], bf[4];
#pragma unroll
      for (int mi=0;mi<4;++mi){
        int ar = mw*64 + mi*16 + (lane&15);
        a[mi] = *(const bf16x8*)&As[ar][(kk*4 + (lane>>4))*8];
      }
#pragma unroll
      for (int ni=0;ni<4;++ni){
        int br = nw*64 + ni*16 + (lane&15);
        bf[ni] = *(const bf16x8*)&Bs[br][(kk*4 + (lane>>4))*8];
      }
#pragma unroll
      for (int mi=0;mi<4;++mi)
#pragma unroll
        for (int ni=0;ni<4;++ni)
          acc[mi][ni] = __builtin_amdgcn_mfma_f32_16x16x32_bf16(a[mi], bf[ni], acc[mi][ni], 0, 0, 0);
    }
    __syncthreads();
  }
#pragma unroll
  for (int mi=0;mi<4;++mi){
#pragma unroll
    for (int r=0;r<4;++r){
      int gr = m0 + mw*64 + mi*16 + (lane>>4)*4 + r;
      size_t orow = (size_t)((gr&15)*32 + (gr>>4)) * VX_;
#pragma unroll
      for (int ni=0;ni<4;++ni){
        int col = n0 + nw*64 + ni*16 + (lane&15);
        out[orow + col] = acc[mi][ni][r] + bias[col];
      }
    }
  }
}

// ============ fused softmax + copy-scatter (no final norm; Σfd = 1 analytically) ============
__global__ __launch_bounds__(256) void k_final(float* __restrict__ out, const float* __restrict__ PTR,
    const float* __restrict__ Q, const float* __restrict__ kgo, const float* __restrict__ kpmask,
    const int* __restrict__ kev, const float* __restrict__ KW){
  const int orow = blockIdx.x;
  const int b = orow >> 5, t = orow & 31;
  const int r = t*16 + b;
  const int tid = threadIdx.x;
  float* f = out + (size_t)orow * VX_;
  __shared__ float qs[512];
  __shared__ float part[256];
  __shared__ float red[256];
  __shared__ float valS[512];
  __shared__ int   idxS[512];
  const float ptr = PTR[r];
  qs[tid] = Q[(size_t)r*512 + tid];
  qs[256 + tid] = Q[(size_t)r*512 + 256 + tid];
  __syncthreads();
  for (int k = 0; k < 8; ++k){
    int l = tid >> 2, qtr = tid & 3;
    const float* kgrow = kgo + (size_t)((b*8 + k)*64 + l) * 512;
    float p = 0.f;
    const float4* q4 = (const float4*)(qs) + qtr*32;
    const float4* k4 = (const float4*)(kgrow) + qtr*32;
#pragma unroll 4
    for (int m=0;m<32;++m){ float4 a=q4[m], c=k4[m]; p += a.x*c.x+a.y*c.y+a.z*c.z+a.w*c.w; }
    part[tid] = p;
    __syncthreads();
    if (tid < 64){
      float ev = part[tid*4]+part[tid*4+1]+part[tid*4+2]+part[tid*4+3];
      if (kpmask[(b*8+k)*64 + tid] == 0.f) ev += NEG_;
      float mx = ev;
#pragma unroll
      for (int off=32;off>0;off>>=1) mx = fmaxf(mx, __shfl_xor(mx, off, 64));
      float ex = __expf(ev - mx);
      float z = ex;
#pragma unroll
      for (int off=32;off>0;off>>=1) z += __shfl_xor(z, off, 64);
      valS[k*64 + tid] = (ex/z) * KW[t*128 + b*8 + k] * (1.f - ptr);
      idxS[k*64 + tid] = kev[(b*8+k)*64 + tid];
    }
    __syncthreads();
  }
  float lm = -1e30f;
  for (int v = tid; v < V_; v += 256) lm = fmaxf(lm, f[v]);
  red[tid] = lm; __syncthreads();
  for (int s=128;s>0;s>>=1){ if (tid<s) red[tid]=fmaxf(red[tid],red[tid+s]); __syncthreads(); }
  float M = red[0]; __syncthreads();
  float ls = 0.f;
  for (int v = tid; v < V_; v += 256){ float e2 = __expf(f[v]-M); f[v] = e2; ls += e2; }
  red[tid] = ls; __syncthreads();
  for (int s=128;s>0;s>>=1){ if (tid<s) red[tid]+=red[tid+s]; __syncthreads(); }
  float scale = ptr / red[0];
  for (int v = tid; v < V_; v += 256) f[v] *= scale;
  for (int v = V_ + tid; v < VX_; v += 256) f[v] = 0.f;
  __syncthreads();
  atomicAdd(f + idxS[tid], valS[tid]);
  atomicAdd(f + idxS[256 + tid], valS[256 + tid]);
}

extern "C" void kernel_launch(void* const* d_in, const int* in_sizes, int n_in,
                              void* d_out, int out_size, void* d_ws, size_t ws_size,
                              hipStream_t stream) {
  const int*   tgt   = (const int*)  d_in[0];
  const float* inith = (const float*)d_in[1];
  const float* src   = (const float*)d_in[2];
  const float* smask = (const float*)d_in[3];
  const float* kgh   = (const float*)d_in[4];
  const float* kgf   = (const float*)d_in[5];
  const float* kgo   = (const float*)d_in[6];
  const float* kmask = (const float*)d_in[7];
  const float* kpmask= (const float*)d_in[8];
  const int*   kev   = (const int*)  d_in[10];
  const float* emb   = (const float*)d_in[12];
  const float* W_ih  = (const float*)d_in[13];
  const float* W_hh  = (const float*)d_in[14];
  const float* b_ih  = (const float*)d_in[15];
  const float* b_hh  = (const float*)d_in[16];
  const float* Wq_c  = (const float*)d_in[17];
  const float* Wv_c  = (const float*)d_in[18];
  const float* bv_c  = (const float*)d_in[19];
  const float* Vw_c  = (const float*)d_in[20];
  const float* bV_c  = (const float*)d_in[21];
  const float* Wq_k  = (const float*)d_in[22];
  const float* Wv_k  = (const float*)d_in[23];
  const float* bv_k  = (const float*)d_in[24];
  const float* Vw_k  = (const float*)d_in[25];
  const float* bV_k  = (const float*)d_in[26];
  const float* W1    = (const float*)d_in[27];
  const float* b1    = (const float*)d_in[28];
  const float* W2    = (const float*)d_in[29];
  const float* b2    = (const float*)d_in[30];
  const float* Wptr  = (const float*)d_in[31];
  const float* bptr  = (const float*)d_in[32];
  const float* Wcpy  = (const float*)d_in[33];
  const float* bcpy  = (const float*)d_in[34];
  float* out = (float*)d_out;

  float* Xb    = (float*)d_ws;            // (T,B,1536)
  float* S_all = Xb    + 786432;          // (T*B,512)
  float* PVS   = S_all + 262144;          // (B,S,512)
  float* PVK   = PVS   + 2097152;         // (B,8,512)
  float* KW    = PVK   + 65536;           // (T,B,8)
  float* GIY   = KW    + 4096;            // (T*B,1536)
  float* CK    = GIY   + 786432;          // (16,1024)
  float* HID   = CK    + 16384;           // (512,512)
  float* Qb    = HID   + 262144;          // (512,512)
  float* PTR   = Qb    + 262144;          // (512)
  float* HQC   = PTR   + 512;             // (16,512)
  float* HQK   = HQC   + 8192;            // (16,512)
  float* GH    = HQK   + 8192;            // (16,1536)
  float* Hbuf  = GH    + 24576;           // (16,512)
  float* Eg    = Hbuf  + 8192;            // (16,256)
  unsigned* CNT = (unsigned*)(Eg + 4096); // 128 instances x 288 u32

  hipMemsetAsync(CNT, 0, 128*BARSTRIDE_*sizeof(unsigned), stream);

  // merged prep: embed ∥ PVS ∥ PVK ∥ GIY
  k_prep<<<1384, 256, 0, stream>>>(emb, tgt, src, Wv_c, bv_c, kgh, Wv_k, bv_k, W_ih,
                                   Xb, PVS, PVK, GIY);

  // persistent recurrence: v4 phases + hierarchical-release barrier
  RP4 rp { inith, src, smask, kgh, kmask, Wq_c, Wq_k, Vw_c, bV_c, Vw_k, bV_k,
           W_ih, W_hh, b_ih, b_hh, PVS, PVK, GIY, Xb, S_all, KW,
           HQC, HQK, GH, CK, Hbuf, Eg, CNT };
  k_recur4<<<NBLK_, 512, 0, stream>>>(rp);

  // merged epilogue-1: W1-GEMM(CAT) ∥ Qb-GEMM ∥ ptr
  k_epi<<<192, 256, 0, stream>>>(S_all, Xb, kgf, W1, b1, Wcpy, bcpy, Wptr, bptr, HID, Qb, PTR);
  // bf16 MFMA logits
  k_logits<<<dim3(2,250), 512, 0, stream>>>(HID, W2, b2, out);
  // fused softmax + scatter (no norm)
  k_final<<<512, 256, 0, stream>>>(out, PTR, Qb, kgo, kpmask, kev, KW);
}

// Round 19
// 1646.806 us; speedup vs baseline: 1.6320x; 1.0222x over previous
//
#include <hip/hip_runtime.h>
#include <hip/hip_bf16.h>

#define B_ 16
#define T_ 32
#define S_ 256
#define K_ 8
#define L_ 64
#define V_ 32000
#define VX_ 32050
#define NEG_ -1e10f
#define NBLK_ 128
#define BARSTRIDE_ 128   // per barrier instance: 4 groups x (counter line + flag line) = 4 x 32 u32

typedef __attribute__((ext_vector_type(8))) __bf16 bf16x8;
typedef __attribute__((ext_vector_type(8))) unsigned short us8;
typedef __attribute__((ext_vector_type(4))) float f32x4;

__device__ __forceinline__ float fsigmoid(float x){ return 1.f/(1.f+__expf(-x)); }
__device__ __forceinline__ float ftanh(float x){ float e=__expf(2.f*x); return 1.f - 2.f/(e+1.f); }
__device__ __forceinline__ unsigned short bf16rne(float f){
  unsigned u = __float_as_uint(f);
  u = u + 0x7FFFu + ((u >> 16) & 1u);
  return (unsigned short)(u >> 16);
}

// ---- LLC-coherent access helpers (device scope via sc0 sc1) ----
__device__ __forceinline__ unsigned ld_llc_u32(const unsigned* p){
  unsigned v;
  asm volatile("global_load_dword %0, %1, off sc0 sc1\n\ts_waitcnt vmcnt(0)" : "=&v"(v) : "v"(p));
  return v;
}
__device__ __forceinline__ void st_llc_u32(unsigned* p, unsigned v){
  asm volatile("global_store_dword %0, %1, off sc0 sc1" :: "v"(p), "v"(v) : "memory");
}
__device__ __forceinline__ float ld_llc_f(const float* p){
  float v;
  asm volatile("global_load_dword %0, %1, off sc0 sc1\n\ts_waitcnt vmcnt(0)" : "=&v"(v) : "v"(p));
  return v;
}
__device__ __forceinline__ f32x4 ld_llc_f4(const float* p){
  f32x4 v;
  asm volatile("global_load_dwordx4 %0, %1, off sc0 sc1\n\ts_waitcnt vmcnt(0)" : "=&v"(v) : "v"(p));
  return v;
}
__device__ __forceinline__ void ld_llc_f4x2(const float* p, f32x4& a, f32x4& b){
  asm volatile("global_load_dwordx4 %0, %2, off sc0 sc1\n\t"
               "global_load_dwordx4 %1, %2, off offset:16 sc0 sc1\n\t"
               "s_waitcnt vmcnt(0)"
               : "=&v"(a), "=&v"(b) : "v"(p));
}
__device__ __forceinline__ void st_llc_f(float* p, float v){
  asm volatile("global_store_dword %0, %1, off sc0 sc1" :: "v"(p), "v"(v) : "memory");
}

// ---- per-batch-group barrier: 32 arrivals; last arriver releases via flag on separate line ----
// The 4 groups (blk>>5) are fully independent pipelines — no cross-group sync needed.
__device__ __forceinline__ void pbar(unsigned* base, int blk){
  asm volatile("s_waitcnt vmcnt(0)" ::: "memory");
  __syncthreads();
  if (threadIdx.x == 0){
    unsigned* cnt  = base + (blk >> 5)*32;   // group counter, own 64B line
    unsigned* flag = cnt + 16;               // group flag, own 64B line
    unsigned old = __hip_atomic_fetch_add(cnt, 1u, __ATOMIC_RELAXED, __HIP_MEMORY_SCOPE_AGENT);
    if (old == 31u){
      st_llc_u32(flag, 1u);
    } else {
      while (ld_llc_u32(flag) == 0u) __builtin_amdgcn_s_sleep(2);
    }
  }
  __syncthreads();
}

// ================= merged prep: embed ∥ PVS-GEMM ∥ PVK-GEMM ∥ GIY-GEMM(embed-gather) =================
__global__ __launch_bounds__(256) void k_prep(const float* __restrict__ emb, const int* __restrict__ tgt,
    const float* __restrict__ src, const float* __restrict__ Wv_c, const float* __restrict__ bv_c,
    const float* __restrict__ kgh, const float* __restrict__ Wv_k, const float* __restrict__ bv_k,
    const float* __restrict__ W_ih,
    float* __restrict__ Xb, float* __restrict__ PVS, float* __restrict__ PVK, float* __restrict__ GIY){
  const int bid = blockIdx.x, tid = threadIdx.x;
  if (bid >= 360){   // embed fill: X[t][b][0:512] = emb[tgt[b][t]]
    int idx = (bid-360)*256 + tid;
    int t = idx >> 13; int b = (idx >> 9) & 15; int e = idx & 511;
    int tok = tgt[b*T_ + t];
    Xb[(size_t)(t*B_+b)*1536 + e] = emb[(size_t)tok*512 + e];
    return;
  }
  __shared__ float As[16][132];
  __shared__ float Ws[16][68];
  const float *A, *W, *bias; float* C; int ldA, ldW, ldC, m0, n0; bool gather = false;
  if (bid < 256){      A=src; ldA=512; W=Wv_c; ldW=512; bias=bv_c; C=PVS; ldC=512;
                       m0=(bid&31)*128; n0=(bid>>5)*64; }
  else if (bid < 264){ A=kgh; ldA=512; W=Wv_k; ldW=512; bias=bv_k; C=PVK; ldC=512;
                       m0=0; n0=(bid-256)*64; }
  else {               gather=true; A=nullptr; ldA=0; W=W_ih; ldW=1536; bias=nullptr; C=GIY; ldC=1536;
                       int g=bid-264; m0=(g&3)*128; n0=(g>>2)*64; }
  const int tm = tid & 15, tn = tid >> 4;
  float acc[8][4];
#pragma unroll
  for (int i=0;i<8;++i)
#pragma unroll
    for(int j=0;j<4;++j) acc[i][j]=0.f;
  for (int k0=0;k0<512;k0+=16){
#pragma unroll
    for (int rr=0;rr<2;++rr){
      int f = tid + rr*256;
      int mm = f >> 2, kc = f & 3;
      int m = m0 + mm;
      const float* ap;
      if (gather){
        int tok = tgt[(m & 15)*T_ + (m >> 4)];
        ap = emb + (size_t)tok*512 + k0 + kc*4;
      } else {
        ap = A + (size_t)m*ldA + k0 + kc*4;
      }
      const float4 v = *(const float4*)ap;
      As[kc*4+0][mm]=v.x; As[kc*4+1][mm]=v.y; As[kc*4+2][mm]=v.z; As[kc*4+3][mm]=v.w;
    }
    {
      int nn = tid >> 2, kc = tid & 3;
      const float4 v = *(const float4*)(W + (size_t)(n0+nn)*ldW + k0 + kc*4);
      Ws[kc*4+0][nn]=v.x; Ws[kc*4+1][nn]=v.y; Ws[kc*4+2][nn]=v.z; Ws[kc*4+3][nn]=v.w;
    }
    __syncthreads();
#pragma unroll
    for (int kk=0;kk<16;++kk){
      float a[8], w[4];
      float4 a0 = *(const float4*)&As[kk][tm*8];
      float4 a1 = *(const float4*)&As[kk][tm*8+4];
      float4 w0 = *(const float4*)&Ws[kk][tn*4];
      a[0]=a0.x;a[1]=a0.y;a[2]=a0.z;a[3]=a0.w;a[4]=a1.x;a[5]=a1.y;a[6]=a1.z;a[7]=a1.w;
      w[0]=w0.x;w[1]=w0.y;w[2]=w0.z;w[3]=w0.w;
#pragma unroll
      for (int i=0;i<8;++i)
#pragma unroll
        for (int j=0;j<4;++j) acc[i][j] += a[i]*w[j];
    }
    __syncthreads();
  }
#pragma unroll
  for (int i=0;i<8;++i){
    int m = m0 + tm*8 + i;
#pragma unroll
    for (int j=0;j<4;++j){
      int n = n0 + tn*4 + j;
      C[(size_t)m*ldC + n] = acc[i][j] + (bias ? bias[n] : 0.f);
    }
  }
}

// ================= persistent recurrence: v4 phases (measured best) + per-group barriers =================
struct RP4 {
  const float *inith, *src, *smask, *kgh, *kmask;
  const float *Wq_c, *Wq_k, *Vw_c, *bV_c, *Vw_k, *bV_k;
  const float *W_ih, *W_hh, *b_ih, *b_hh;
  const float *PVS, *PVK, *GIY;
  float *Xb, *S_all, *KW;
  float *HQC, *HQK, *GH, *CK, *Hbuf, *Eg;
  unsigned *cnt;
};

__global__ __launch_bounds__(512) void k_recur4(RP4 p){
  __shared__ float SH[4608];
  const int tid = threadIdx.x;
  const int blk = blockIdx.x;
  const float bVc = p.bV_c[0], bVk = p.bV_k[0];

  for (int t = 0; t < T_; ++t){
    // ======== P1: block = (rg 0..31) x (bg 0..3): rows rg*80..+80, batches bg*4..+4 ========
    {
      const int rg = blk & 31, bg = blk >> 5;
      float* hS = SH;   // 4 x 516 = 2064 floats (LDS-safe)
      {
        int i0 = tid*4; int bb = i0 >> 9, cc = i0 & 511;
        float vx,vy,vz,vw;
        if (t == 0){
          float4 v = *(const float4*)(p.inith + (size_t)(bg*4+bb)*512 + cc);
          vx=v.x; vy=v.y; vz=v.z; vw=v.w;
        } else {
          f32x4 v = ld_llc_f4(p.Hbuf + (size_t)(bg*4+bb)*512 + cc);
          vx=v[0]; vy=v[1]; vz=v[2]; vw=v[3];
        }
        hS[bb*516+cc]=vx; hS[bb*516+cc+1]=vy; hS[bb*516+cc+2]=vz; hS[bb*516+cc+3]=vw;
      }
      __syncthreads();
      int rl = tid >> 2, bl = tid & 3;
      if (rl < 80){
        int R = rg*80 + rl;
        const float* wrow = (R < 512) ? (p.Wq_c + (size_t)R*512)
                          : (R < 1024) ? (p.Wq_k + (size_t)(R-512)*512)
                          : (p.W_hh + (size_t)(R-1024)*512);
        const float* hb = hS + bl*516;
        float s = 0.f;
#pragma unroll 8
        for (int m=0;m<128;++m){
          float4 w = *(const float4*)(wrow + m*4);
          float4 hv = *(const float4*)(hb + m*4);
          s += w.x*hv.x + w.y*hv.y + w.z*hv.z + w.w*hv.w;
        }
        int b = bg*4 + bl;
        if (R < 512)       st_llc_f(p.HQC + b*512 + R, s);
        else if (R < 1024) st_llc_f(p.HQK + b*512 + (R-512), s);
        else               st_llc_f(p.GH + b*1536 + (R-1024), s + p.b_hh[R-1024]);
      }
    }
    pbar(p.cnt + (4*t)*BARSTRIDE_, blk);

    // ======== P2: e_src — block = (b 0..15) x (pg 0..7): positions pg*32..+32, 16 thr/row ========
    {
      const int b2 = blk >> 3, pg = blk & 7;
      float* hqcS = SH;        // 16 chunks x 33
      float* vwcS = SH + 528;
      {
        int q = tid >> 5, ii = tid & 31;
        if (tid < 512){
          hqcS[q*33+ii] = ld_llc_f(p.HQC + b2*512 + tid);
          vwcS[q*33+ii] = p.Vw_c[tid];
        }
      }
      __syncthreads();
      int pp = tid >> 4, q = tid & 15;
      int s_i = pg*32 + pp;
      const float4* pv4 = (const float4*)(p.PVS + ((size_t)(b2*S_ + s_i))*512 + q*32);
      const float* hq = hqcS + q*33;
      const float* vw = vwcS + q*33;
      float pe = 0.f;
#pragma unroll
      for (int m=0;m<8;++m){
        float4 v = pv4[m];
        int i0 = m*4;
        pe += ftanh(v.x+hq[i0+0])*vw[i0+0] + ftanh(v.y+hq[i0+1])*vw[i0+1]
            + ftanh(v.z+hq[i0+2])*vw[i0+2] + ftanh(v.w+hq[i0+3])*vw[i0+3];
      }
      pe += __shfl_down(pe, 8, 16);
      pe += __shfl_down(pe, 4, 16);
      pe += __shfl_down(pe, 2, 16);
      pe += __shfl_down(pe, 1, 16);
      if (q == 0){
        float v = pe + bVc;
        if (p.smask[b2*S_ + s_i] == 0.f) v += NEG_;
        st_llc_f(p.Eg + b2*S_ + s_i, v);
      }
    }
    pbar(p.cnt + (4*t+1)*BARSTRIDE_, blk);

    // ======== P3: softmax + c_t/k_t — block = (b 0..15) x (jg 0..7): cols jg*64..+64 ========
    {
      const int b3 = blk >> 3, jg = blk & 7, j0 = jg*64;
      float* eS    = SH;          // 256
      float* wS    = SH + 256;    // 256
      float* hqkS  = SH + 512;    // 64x9 = 576
      float* vwkS  = SH + 1088;   // 576
      float* partS = SH + 1664;   // 512
      float* ekS   = SH + 2176;   // 8
      float* kwS   = SH + 2184;   // 8
      float* MZ    = SH + 2192;   // 2
      if (tid < 64){
        f32x4 v = ld_llc_f4(p.Eg + b3*S_ + tid*4);
        eS[tid*4]=v[0]; eS[tid*4+1]=v[1]; eS[tid*4+2]=v[2]; eS[tid*4+3]=v[3];
      }
      {
        int part = tid >> 3, ii = tid & 7;
        hqkS[part*9+ii] = ld_llc_f(p.HQK + b3*512 + tid);
        vwkS[part*9+ii] = p.Vw_k[tid];
      }
      __syncthreads();
      if (tid < 64){
        float4 e4 = *(const float4*)&eS[tid*4];
        float m = fmaxf(fmaxf(e4.x,e4.y), fmaxf(e4.z,e4.w));
#pragma unroll
        for (int off=32; off>0; off>>=1) m = fmaxf(m, __shfl_xor(m, off, 64));
        float z = __expf(e4.x-m)+__expf(e4.y-m)+__expf(e4.z-m)+__expf(e4.w-m);
#pragma unroll
        for (int off=32; off>0; off>>=1) z += __shfl_xor(z, off, 64);
        if (tid == 0){ MZ[0] = m; MZ[1] = z; }
      }
      {
        int key = tid >> 6, part = tid & 63;
        const float4* pk4 = (const float4*)(p.PVK + ((size_t)(b3*K_ + key))*512 + part*8);
        float4 va = pk4[0], vb = pk4[1];
        const float* hq = hqkS + part*9;
        const float* vw = vwkS + part*9;
        float s2 = ftanh(va.x+hq[0])*vw[0] + ftanh(va.y+hq[1])*vw[1]
                 + ftanh(va.z+hq[2])*vw[2] + ftanh(va.w+hq[3])*vw[3]
                 + ftanh(vb.x+hq[4])*vw[4] + ftanh(vb.y+hq[5])*vw[5]
                 + ftanh(vb.z+hq[6])*vw[6] + ftanh(vb.w+hq[7])*vw[7];
#pragma unroll
        for (int off=32; off>0; off>>=1) s2 += __shfl_xor(s2, off, 64);
        if (part == 0){
          float v = s2 + bVk;
          if (p.kmask[b3*K_ + key] == 0.f) v += NEG_;
          ekS[key] = v;
        }
      }
      __syncthreads();
      if (tid == 0){
        float mk = -1e30f;
#pragma unroll
        for (int k=0;k<8;++k) mk = fmaxf(mk, ekS[k]);
        float z = 0.f; float tmp[8];
#pragma unroll
        for (int k=0;k<8;++k){ tmp[k] = __expf(ekS[k]-mk); z += tmp[k]; }
        float iz = 1.f/z;
#pragma unroll
        for (int k=0;k<8;++k) kwS[k] = tmp[k]*iz;
      }
      __syncthreads();
      float Mv = MZ[0], invZ = 1.f/MZ[1];
      if (tid < 256) wS[tid] = __expf(eS[tid]-Mv);
      __syncthreads();
      {
        int sg = tid >> 6, jl = tid & 63;
        const float* sp = p.src + ((size_t)(b3*S_ + sg*32))*512 + j0 + jl;
        float acc = 0.f;
#pragma unroll 8
        for (int i=0;i<32;++i) acc += wS[sg*32+i] * sp[(size_t)i*512];
        partS[sg*64 + jl] = acc;
      }
      __syncthreads();
      if (tid < 64){
        float c = 0.f;
#pragma unroll
        for (int sg=0; sg<8; ++sg) c += partS[sg*64 + tid];
        c *= invZ;
        float kt = 0.f;
#pragma unroll
        for (int k=0;k<8;++k) kt += kwS[k] * p.kgh[((size_t)(b3*K_+k))*512 + j0 + tid];
        float* Xbt = p.Xb + ((size_t)t*16 + b3)*1536;
        Xbt[512 + j0 + tid]  = c;
        Xbt[1024 + j0 + tid] = kt;
        st_llc_f(p.CK + b3*1024 + j0 + tid, c);
        st_llc_f(p.CK + b3*1024 + 512 + j0 + tid, kt);
      }
      if (jg == 0 && tid < 8) p.KW[t*128 + b3*8 + tid] = kwS[tid];
    }
    pbar(p.cnt + (4*t+2)*BARSTRIDE_, blk);

    // ======== P4: GRU — block = (rg2 0..31) x (bg2 0..3): cols rg2*16..+16, batches bg2*4..+4 ========
    {
      const int rg2 = blk & 31, bg2 = blk >> 5;
      const int j0 = rg2*16, bb0 = bg2*4;
      float* ckS = SH;          // 4 x 1028
      float* giS = SH + 4112;   // 48 x 4
      float* ghS = SH + 4304;   // 48 x 4
      {
        int i0 = tid*8; int bb = i0 >> 10, cc = i0 & 1023;
        f32x4 a, b4;
        ld_llc_f4x2(p.CK + (size_t)(bb0+bb)*1024 + cc, a, b4);
        float* d = ckS + bb*1028 + cc;
        d[0]=a[0]; d[1]=a[1]; d[2]=a[2]; d[3]=a[3];
        d[4]=b4[0]; d[5]=b4[1]; d[6]=b4[2]; d[7]=b4[3];
      }
      __syncthreads();
      int pair = tid >> 1, ks = tid & 1;
      float gi = 0.f;
      int row = 0, bloc = 0, rw = 0;
      if (pair < 192){
        rw = pair >> 2; bloc = pair & 3;
        row = (rw >> 4)*512 + j0 + (rw & 15);
        const float4* wi4 = (const float4*)(p.W_ih + (size_t)row*1536 + 512 + ks*512);
        const float* ckb = ckS + bloc*1028 + ks*512;
#pragma unroll 8
        for (int m=0;m<128;++m){
          float4 w = wi4[m];
          gi += w.x*ckb[m*4] + w.y*ckb[m*4+1] + w.z*ckb[m*4+2] + w.w*ckb[m*4+3];
        }
      }
      gi += __shfl_xor(gi, 1, 64);
      if (pair < 192 && ks == 0){
        int b = bb0 + bloc;
        giS[rw*4 + bloc] = gi + p.GIY[((size_t)t*16 + b)*1536 + row] + p.b_ih[row];
        ghS[rw*4 + bloc] = ld_llc_f(p.GH + b*1536 + row);
      }
      __syncthreads();
      if (tid < 64){
        int jl = tid >> 2, bl2 = tid & 3;
        int b = bb0 + bl2, j = j0 + jl;
        float gir = giS[jl*4+bl2],      giz = giS[(16+jl)*4+bl2],  gin = giS[(32+jl)*4+bl2];
        float ghr = ghS[jl*4+bl2],      ghz = ghS[(16+jl)*4+bl2],  ghn = ghS[(32+jl)*4+bl2];
        float r = fsigmoid(gir + ghr);
        float z = fsigmoid(giz + ghz);
        float n = ftanh(gin + r*ghn);
        float hold = (t == 0) ? p.inith[b*512 + j] : ld_llc_f(p.Hbuf + b*512 + j);
        float hn = (1.f - z)*n + z*hold;
        p.S_all[((size_t)t*16 + b)*512 + j] = hn;
        st_llc_f(p.Hbuf + b*512 + j, hn);
      }
    }
    pbar(p.cnt + (4*t+3)*BARSTRIDE_, blk);
  }
}

// ================= merged epilogue-1: W1-GEMM(CAT-gather) ∥ Qb-GEMM ∥ ptr =================
__global__ __launch_bounds__(256) void k_epi(const float* __restrict__ S_all, const float* __restrict__ X,
    const float* __restrict__ kgf, const float* __restrict__ W1, const float* __restrict__ b1,
    const float* __restrict__ Wcpy, const float* __restrict__ bcpy,
    const float* __restrict__ Wptr, const float* __restrict__ bptr,
    float* __restrict__ HID, float* __restrict__ Qb, float* __restrict__ PTR){
  const int bid = blockIdx.x, tid = threadIdx.x;
  if (bid >= 64){   // ptr: rows (bid-64)*4 .. +4
    int r = (bid-64)*4 + (tid >> 6);
    int lane = tid & 63;
    const float* seg[5];
    seg[0] = X + (size_t)r*1536 + 512;
    seg[1] = S_all + (size_t)r*512;
    seg[2] = X + (size_t)r*1536;
    seg[3] = kgf + (size_t)(r & 15)*512;
    seg[4] = X + (size_t)r*1536 + 1024;
    float s = 0.f;
#pragma unroll
    for (int g=0; g<5; ++g){
      const float* p = seg[g];
      const float* w = Wptr + g*512;
#pragma unroll
      for (int m=0;m<8;++m){ int i = lane + m*64; s += p[i]*w[i]; }
    }
#pragma unroll
    for (int off=32;off>0;off>>=1) s += __shfl_down(s, off, 64);
    if (lane == 0) PTR[r] = fsigmoid(s + bptr[0]);
    return;
  }
  __shared__ float As[16][132];
  __shared__ float Ws[16][68];
  const bool isW1 = (bid < 32);
  const int g = isW1 ? bid : bid-32;
  const int m0 = (g&3)*128, n0 = (g>>2)*64;
  const int KK = isW1 ? 2048 : 512;
  const float* W = isW1 ? W1 : Wcpy;
  const float* bias = isW1 ? b1 : bcpy;
  float* C = isW1 ? HID : Qb;
  const int tm = tid & 15, tn = tid >> 4;
  float acc[8][4];
#pragma unroll
  for (int i=0;i<8;++i)
#pragma unroll
    for(int j=0;j<4;++j) acc[i][j]=0.f;
  for (int k0=0;k0<KK;k0+=16){
#pragma unroll
    for (int rr=0;rr<2;++rr){
      int f = tid + rr*256;
      int mm = f >> 2, kc = f & 3;
      int m = m0 + mm, col = k0 + kc*4;
      const float* ap;
      if (!isW1)            ap = S_all + (size_t)m*512 + col;
      else if (col < 512)   ap = S_all + (size_t)m*512 + col;
      else if (col < 1536)  ap = X + (size_t)m*1536 + col;
      else                  ap = kgf + (size_t)(m & 15)*512 + (col - 1536);
      const float4 v = *(const float4*)ap;
      As[kc*4+0][mm]=v.x; As[kc*4+1][mm]=v.y; As[kc*4+2][mm]=v.z; As[kc*4+3][mm]=v.w;
    }
    {
      int nn = tid >> 2, kc = tid & 3;
      const float4 v = *(const float4*)(W + (size_t)(n0+nn)*KK + k0 + kc*4);
      Ws[kc*4+0][nn]=v.x; Ws[kc*4+1][nn]=v.y; Ws[kc*4+2][nn]=v.z; Ws[kc*4+3][nn]=v.w;
    }
    __syncthreads();
#pragma unroll
    for (int kk=0;kk<16;++kk){
      float a[8], w[4];
      float4 a0 = *(const float4*)&As[kk][tm*8];
      float4 a1 = *(const float4*)&As[kk][tm*8+4];
      float4 w0 = *(const float4*)&Ws[kk][tn*4];
      a[0]=a0.x;a[1]=a0.y;a[2]=a0.z;a[3]=a0.w;a[4]=a1.x;a[5]=a1.y;a[6]=a1.z;a[7]=a1.w;
      w[0]=w0.x;w[1]=w0.y;w[2]=w0.z;w[3]=w0.w;
#pragma unroll
      for (int i=0;i<8;++i)
#pragma unroll
        for (int j=0;j<4;++j) acc[i][j] += a[i]*w[j];
    }
    __syncthreads();
  }
#pragma unroll
  for (int i=0;i<8;++i){
    int m = m0 + tm*8 + i;
#pragma unroll
    for (int j=0;j<4;++j){
      int n = n0 + tn*4 + j;
      C[(size_t)m*512 + n] = acc[i][j] + bias[n];
    }
  }
}

// ============ bf16 MFMA logits GEMM, f32 inputs converted inline (verified) ============
__global__ __launch_bounds__(512) void k_logits(const float* __restrict__ A,
    const float* __restrict__ Bf, const float* __restrict__ bias, float* __restrict__ out){
  __shared__ unsigned short As[256][72];
  __shared__ unsigned short Bs[128][72];
  const int tid = threadIdx.x;
  const int m0 = blockIdx.x*256, n0 = blockIdx.y*128;
  const int lane = tid & 63, wid = tid >> 6;
  const int mw = wid >> 1, nw = wid & 1;
  f32x4 acc[4][4];
#pragma unroll
  for (int i=0;i<4;++i)
#pragma unroll
    for (int j=0;j<4;++j) acc[i][j] = (f32x4){0.f,0.f,0.f,0.f};
  for (int k0 = 0; k0 < 512; k0 += 64){
#pragma unroll
    for (int i=0;i<4;++i){
      int v = i*512 + tid; int row = v >> 3, vc = v & 7;
      const float* srcp = A + (size_t)(m0+row)*512 + k0 + vc*8;
      float4 f0 = *(const float4*)srcp, f1 = *(const float4*)(srcp+4);
      us8 d;
      d[0]=bf16rne(f0.x); d[1]=bf16rne(f0.y); d[2]=bf16rne(f0.z); d[3]=bf16rne(f0.w);
      d[4]=bf16rne(f1.x); d[5]=bf16rne(f1.y); d[6]=bf16rne(f1.z); d[7]=bf16rne(f1.w);
      *(us8*)&As[row][vc*8] = d;
    }
#pragma unroll
    for (int i=0;i<2;++i){
      int v = i*512 + tid; int row = v >> 3, vc = v & 7;
      const float* srcp = Bf + (size_t)(n0+row)*512 + k0 + vc*8;
      float4 f0 = *(const float4*)srcp, f1 = *(const float4*)(srcp+4);
      us8 d;
      d[0]=bf16rne(f0.x); d[1]=bf16rne(f0.y); d[2]=bf16rne(f0.z); d[3]=bf16rne(f0.w);
      d[4]=bf16rne(f1.x); d[5]=bf16rne(f1.y); d[6]=bf16rne(f1.z); d[7]=bf16rne(f1.w);
      *(us8*)&Bs[row][vc*8] = d;
    }
    __syncthreads();
#pragma unroll
    for (int kk=0;kk<2;++kk){
      bf16x8 a[4], bf[4];
#pragma unroll
      for (int mi=0;mi<4;++mi){
        int ar = mw*64 + mi*16 + (lane&15);
        a[mi] = *(const bf16x8*)&As[ar][(kk*4 + (lane>>4))*8];
      }
#pragma unroll
      for (int ni=0;ni<4;++ni){
        int br = nw*64 + ni*16 + (lane&15);
        bf[ni] = *(const bf16x8*)&Bs[br][(kk*4 + (lane>>4))*8];
      }
#pragma unroll
      for (int mi=0;mi<4;++mi)
#pragma unroll
        for (int ni=0;ni<4;++ni)
          acc[mi][ni] = __builtin_amdgcn_mfma_f32_16x16x32_bf16(a[mi], bf[ni], acc[mi][ni], 0, 0, 0);
    }
    __syncthreads();
  }
#pragma unroll
  for (int mi=0;mi<4;++mi){
#pragma unroll
    for (int r=0;r<4;++r){
      int gr = m0 + mw*64 + mi*16 + (lane>>4)*4 + r;
      size_t orow = (size_t)((gr&15)*32 + (gr>>4)) * VX_;
#pragma unroll
      for (int ni=0;ni<4;++ni){
        int col = n0 + nw*64 + ni*16 + (lane&15);
        out[orow + col] = acc[mi][ni][r] + bias[col];
      }
    }
  }
}

// ============ fused softmax + copy-scatter (no final norm; Σfd = 1 analytically) ============
__global__ __launch_bounds__(256) void k_final(float* __restrict__ out, const float* __restrict__ PTR,
    const float* __restrict__ Q, const float* __restrict__ kgo, const float* __restrict__ kpmask,
    const int* __restrict__ kev, const float* __restrict__ KW){
  const int orow = blockIdx.x;
  const int b = orow >> 5, t = orow & 31;
  const int r = t*16 + b;
  const int tid = threadIdx.x;
  float* f = out + (size_t)orow * VX_;
  __shared__ float qs[512];
  __shared__ float part[256];
  __shared__ float red[256];
  __shared__ float valS[512];
  __shared__ int   idxS[512];
  const float ptr = PTR[r];
  qs[tid] = Q[(size_t)r*512 + tid];
  qs[256 + tid] = Q[(size_t)r*512 + 256 + tid];
  __syncthreads();
  for (int k = 0; k < 8; ++k){
    int l = tid >> 2, qtr = tid & 3;
    const float* kgrow = kgo + (size_t)((b*8 + k)*64 + l) * 512;
    float p = 0.f;
    const float4* q4 = (const float4*)(qs) + qtr*32;
    const float4* k4 = (const float4*)(kgrow) + qtr*32;
#pragma unroll 4
    for (int m=0;m<32;++m){ float4 a=q4[m], c=k4[m]; p += a.x*c.x+a.y*c.y+a.z*c.z+a.w*c.w; }
    part[tid] = p;
    __syncthreads();
    if (tid < 64){
      float ev = part[tid*4]+part[tid*4+1]+part[tid*4+2]+part[tid*4+3];
      if (kpmask[(b*8+k)*64 + tid] == 0.f) ev += NEG_;
      float mx = ev;
#pragma unroll
      for (int off=32;off>0;off>>=1) mx = fmaxf(mx, __shfl_xor(mx, off, 64));
      float ex = __expf(ev - mx);
      float z = ex;
#pragma unroll
      for (int off=32;off>0;off>>=1) z += __shfl_xor(z, off, 64);
      valS[k*64 + tid] = (ex/z) * KW[t*128 + b*8 + k] * (1.f - ptr);
      idxS[k*64 + tid] = kev[(b*8+k)*64 + tid];
    }
    __syncthreads();
  }
  float lm = -1e30f;
  for (int v = tid; v < V_; v += 256) lm = fmaxf(lm, f[v]);
  red[tid] = lm; __syncthreads();
  for (int s=128;s>0;s>>=1){ if (tid<s) red[tid]=fmaxf(red[tid],red[tid+s]); __syncthreads(); }
  float M = red[0]; __syncthreads();
  float ls = 0.f;
  for (int v = tid; v < V_; v += 256){ float e2 = __expf(f[v]-M); f[v] = e2; ls += e2; }
  red[tid] = ls; __syncthreads();
  for (int s=128;s>0;s>>=1){ if (tid<s) red[tid]+=red[tid+s]; __syncthreads(); }
  float scale = ptr / red[0];
  for (int v = tid; v < V_; v += 256) f[v] *= scale;
  for (int v = V_ + tid; v < VX_; v += 256) f[v] = 0.f;
  __syncthreads();
  atomicAdd(f + idxS[tid], valS[tid]);
  atomicAdd(f + idxS[256 + tid], valS[256 + tid]);
}

extern "C" void kernel_launch(void* const* d_in, const int* in_sizes, int n_in,
                              void* d_out, int out_size, void* d_ws, size_t ws_size,
                              hipStream_t stream) {
  const int*   tgt   = (const int*)  d_in[0];
  const float* inith = (const float*)d_in[1];
  const float* src   = (const float*)d_in[2];
  const float* smask = (const float*)d_in[3];
  const float* kgh   = (const float*)d_in[4];
  const float* kgf   = (const float*)d_in[5];
  const float* kgo   = (const float*)d_in[6];
  const float* kmask = (const float*)d_in[7];
  const float* kpmask= (const float*)d_in[8];
  const int*   kev   = (const int*)  d_in[10];
  const float* emb   = (const float*)d_in[12];
  const float* W_ih  = (const float*)d_in[13];
  const float* W_hh  = (const float*)d_in[14];
  const float* b_ih  = (const float*)d_in[15];
  const float* b_hh  = (const float*)d_in[16];
  const float* Wq_c  = (const float*)d_in[17];
  const float* Wv_c  = (const float*)d_in[18];
  const float* bv_c  = (const float*)d_in[19];
  const float* Vw_c  = (const float*)d_in[20];
  const float* bV_c  = (const float*)d_in[21];
  const float* Wq_k  = (const float*)d_in[22];
  const float* Wv_k  = (const float*)d_in[23];
  const float* bv_k  = (const float*)d_in[24];
  const float* Vw_k  = (const float*)d_in[25];
  const float* bV_k  = (const float*)d_in[26];
  const float* W1    = (const float*)d_in[27];
  const float* b1    = (const float*)d_in[28];
  const float* W2    = (const float*)d_in[29];
  const float* b2    = (const float*)d_in[30];
  const float* Wptr  = (const float*)d_in[31];
  const float* bptr  = (const float*)d_in[32];
  const float* Wcpy  = (const float*)d_in[33];
  const float* bcpy  = (const float*)d_in[34];
  float* out = (float*)d_out;

  float* Xb    = (float*)d_ws;            // (T,B,1536)
  float* S_all = Xb    + 786432;          // (T*B,512)
  float* PVS   = S_all + 262144;          // (B,S,512)
  float* PVK   = PVS   + 2097152;         // (B,8,512)
  float* KW    = PVK   + 65536;           // (T,B,8)
  float* GIY   = KW    + 4096;            // (T*B,1536)
  float* CK    = GIY   + 786432;          // (16,1024)
  float* HID   = CK    + 16384;           // (512,512)
  float* Qb    = HID   + 262144;          // (512,512)
  float* PTR   = Qb    + 262144;          // (512)
  float* HQC   = PTR   + 512;             // (16,512)
  float* HQK   = HQC   + 8192;            // (16,512)
  float* GH    = HQK   + 8192;            // (16,1536)
  float* Hbuf  = GH    + 24576;           // (16,512)
  float* Eg    = Hbuf  + 8192;            // (16,256)
  unsigned* CNT = (unsigned*)(Eg + 4096); // 128 instances x 128 u32 (4 groups x 2 lines)

  hipMemsetAsync(CNT, 0, 128*BARSTRIDE_*sizeof(unsigned), stream);

  // merged prep: embed ∥ PVS ∥ PVK ∥ GIY
  k_prep<<<1384, 256, 0, stream>>>(emb, tgt, src, Wv_c, bv_c, kgh, Wv_k, bv_k, W_ih,
                                   Xb, PVS, PVK, GIY);

  // persistent recurrence: v4 phases + per-group (32-block) barriers
  RP4 rp { inith, src, smask, kgh, kmask, Wq_c, Wq_k, Vw_c, bV_c, Vw_k, bV_k,
           W_ih, W_hh, b_ih, b_hh, PVS, PVK, GIY, Xb, S_all, KW,
           HQC, HQK, GH, CK, Hbuf, Eg, CNT };
  k_recur4<<<NBLK_, 512, 0, stream>>>(rp);

  // merged epilogue-1: W1-GEMM(CAT) ∥ Qb-GEMM ∥ ptr
  k_epi<<<192, 256, 0, stream>>>(S_all, Xb, kgf, W1, b1, Wcpy, bcpy, Wptr, bptr, HID, Qb, PTR);
  // bf16 MFMA logits
  k_logits<<<dim3(2,250), 512, 0, stream>>>(HID, W2, b2, out);
  // fused softmax + scatter (no norm)
  k_final<<<512, 256, 0, stream>>>(out, PTR, Qb, kgo, kpmask, kev, KW);
}

// Round 20
// 1642.902 us; speedup vs baseline: 1.6358x; 1.0024x over previous
//
#include <hip/hip_runtime.h>
#include <hip/hip_bf16.h>

#define B_ 16
#define T_ 32
#define S_ 256
#define K_ 8
#define L_ 64
#define V_ 32000
#define VX_ 32050
#define NEG_ -1e10f
#define NBLK_ 128
#define BARSTRIDE_ 128   // per barrier instance: 4 groups x (counter line + flag line) = 4 x 32 u32

typedef __attribute__((ext_vector_type(8))) __bf16 bf16x8;
typedef __attribute__((ext_vector_type(8))) unsigned short us8;
typedef __attribute__((ext_vector_type(4))) float f32x4;

__device__ __forceinline__ float fsigmoid(float x){ return 1.f/(1.f+__expf(-x)); }
__device__ __forceinline__ float ftanh(float x){ float e=__expf(2.f*x); return 1.f - 2.f/(e+1.f); }
__device__ __forceinline__ unsigned short bf16rne(float f){
  unsigned u = __float_as_uint(f);
  u = u + 0x7FFFu + ((u >> 16) & 1u);
  return (unsigned short)(u >> 16);
}

// ---- LLC-coherent access helpers (device scope via sc0 sc1) ----
__device__ __forceinline__ unsigned ld_llc_u32(const unsigned* p){
  unsigned v;
  asm volatile("global_load_dword %0, %1, off sc0 sc1\n\ts_waitcnt vmcnt(0)" : "=&v"(v) : "v"(p));
  return v;
}
__device__ __forceinline__ void st_llc_u32(unsigned* p, unsigned v){
  asm volatile("global_store_dword %0, %1, off sc0 sc1" :: "v"(p), "v"(v) : "memory");
}
__device__ __forceinline__ float ld_llc_f(const float* p){
  float v;
  asm volatile("global_load_dword %0, %1, off sc0 sc1\n\ts_waitcnt vmcnt(0)" : "=&v"(v) : "v"(p));
  return v;
}
__device__ __forceinline__ f32x4 ld_llc_f4(const float* p){
  f32x4 v;
  asm volatile("global_load_dwordx4 %0, %1, off sc0 sc1\n\ts_waitcnt vmcnt(0)" : "=&v"(v) : "v"(p));
  return v;
}
__device__ __forceinline__ void ld_llc_f4x2(const float* p, f32x4& a, f32x4& b){
  asm volatile("global_load_dwordx4 %0, %2, off sc0 sc1\n\t"
               "global_load_dwordx4 %1, %2, off offset:16 sc0 sc1\n\t"
               "s_waitcnt vmcnt(0)"
               : "=&v"(a), "=&v"(b) : "v"(p));
}
__device__ __forceinline__ void st_llc_f(float* p, float v){
  asm volatile("global_store_dword %0, %1, off sc0 sc1" :: "v"(p), "v"(v) : "memory");
}

// ---- per-batch-group barrier: 32 arrivals; last arriver releases via flag on separate line ----
__device__ __forceinline__ void pbar(unsigned* base, int blk){
  asm volatile("s_waitcnt vmcnt(0)" ::: "memory");
  __syncthreads();
  if (threadIdx.x == 0){
    unsigned* cnt  = base + (blk >> 5)*32;   // group counter, own 64B line
    unsigned* flag = cnt + 16;               // group flag, own 64B line
    unsigned old = __hip_atomic_fetch_add(cnt, 1u, __ATOMIC_RELAXED, __HIP_MEMORY_SCOPE_AGENT);
    if (old == 31u){
      st_llc_u32(flag, 1u);
    } else {
      while (ld_llc_u32(flag) == 0u) __builtin_amdgcn_s_sleep(2);
    }
  }
  __syncthreads();
}

// ================= merged prep: embed ∥ PVS-GEMM ∥ PVK-GEMM ∥ GIY-GEMM(embed-gather) =================
__global__ __launch_bounds__(256) void k_prep(const float* __restrict__ emb, const int* __restrict__ tgt,
    const float* __restrict__ src, const float* __restrict__ Wv_c, const float* __restrict__ bv_c,
    const float* __restrict__ kgh, const float* __restrict__ Wv_k, const float* __restrict__ bv_k,
    const float* __restrict__ W_ih,
    float* __restrict__ Xb, float* __restrict__ PVS, float* __restrict__ PVK, float* __restrict__ GIY){
  const int bid = blockIdx.x, tid = threadIdx.x;
  if (bid >= 360){   // embed fill: X[t][b][0:512] = emb[tgt[b][t]]
    int idx = (bid-360)*256 + tid;
    int t = idx >> 13; int b = (idx >> 9) & 15; int e = idx & 511;
    int tok = tgt[b*T_ + t];
    Xb[(size_t)(t*B_+b)*1536 + e] = emb[(size_t)tok*512 + e];
    return;
  }
  __shared__ float As[16][132];
  __shared__ float Ws[16][68];
  const float *A, *W, *bias; float* C; int ldA, ldW, ldC, m0, n0; bool gather = false;
  if (bid < 256){      A=src; ldA=512; W=Wv_c; ldW=512; bias=bv_c; C=PVS; ldC=512;
                       m0=(bid&31)*128; n0=(bid>>5)*64; }
  else if (bid < 264){ A=kgh; ldA=512; W=Wv_k; ldW=512; bias=bv_k; C=PVK; ldC=512;
                       m0=0; n0=(bid-256)*64; }
  else {               gather=true; A=nullptr; ldA=0; W=W_ih; ldW=1536; bias=nullptr; C=GIY; ldC=1536;
                       int g=bid-264; m0=(g&3)*128; n0=(g>>2)*64; }
  const int tm = tid & 15, tn = tid >> 4;
  float acc[8][4];
#pragma unroll
  for (int i=0;i<8;++i)
#pragma unroll
    for(int j=0;j<4;++j) acc[i][j]=0.f;
  for (int k0=0;k0<512;k0+=16){
#pragma unroll
    for (int rr=0;rr<2;++rr){
      int f = tid + rr*256;
      int mm = f >> 2, kc = f & 3;
      int m = m0 + mm;
      const float* ap;
      if (gather){
        int tok = tgt[(m & 15)*T_ + (m >> 4)];
        ap = emb + (size_t)tok*512 + k0 + kc*4;
      } else {
        ap = A + (size_t)m*ldA + k0 + kc*4;
      }
      const float4 v = *(const float4*)ap;
      As[kc*4+0][mm]=v.x; As[kc*4+1][mm]=v.y; As[kc*4+2][mm]=v.z; As[kc*4+3][mm]=v.w;
    }
    {
      int nn = tid >> 2, kc = tid & 3;
      const float4 v = *(const float4*)(W + (size_t)(n0+nn)*ldW + k0 + kc*4);
      Ws[kc*4+0][nn]=v.x; Ws[kc*4+1][nn]=v.y; Ws[kc*4+2][nn]=v.z; Ws[kc*4+3][nn]=v.w;
    }
    __syncthreads();
#pragma unroll
    for (int kk=0;kk<16;++kk){
      float a[8], w[4];
      float4 a0 = *(const float4*)&As[kk][tm*8];
      float4 a1 = *(const float4*)&As[kk][tm*8+4];
      float4 w0 = *(const float4*)&Ws[kk][tn*4];
      a[0]=a0.x;a[1]=a0.y;a[2]=a0.z;a[3]=a0.w;a[4]=a1.x;a[5]=a1.y;a[6]=a1.z;a[7]=a1.w;
      w[0]=w0.x;w[1]=w0.y;w[2]=w0.z;w[3]=w0.w;
#pragma unroll
      for (int i=0;i<8;++i)
#pragma unroll
        for (int j=0;j<4;++j) acc[i][j] += a[i]*w[j];
    }
    __syncthreads();
  }
#pragma unroll
  for (int i=0;i<8;++i){
    int m = m0 + tm*8 + i;
#pragma unroll
    for (int j=0;j<4;++j){
      int n = n0 + tn*4 + j;
      C[(size_t)m*ldC + n] = acc[i][j] + (bias ? bias[n] : 0.f);
    }
  }
}

// ================= persistent recurrence: v4 phases (measured best) + per-group barriers =================
struct RP4 {
  const float *inith, *src, *smask, *kgh, *kmask;
  const float *Wq_c, *Wq_k, *Vw_c, *bV_c, *Vw_k, *bV_k;
  const float *W_ih, *W_hh, *b_ih, *b_hh;
  const float *PVS, *PVK, *GIY;
  float *Xb, *S_all, *KW;
  float *HQC, *HQK, *GH, *CK, *Hbuf, *Eg;
  unsigned *cnt;
};

__global__ __launch_bounds__(512) void k_recur4(RP4 p){
  __shared__ float SH[4608];
  const int tid = threadIdx.x;
  const int blk = blockIdx.x;
  const float bVc = p.bV_c[0], bVk = p.bV_k[0];

  for (int t = 0; t < T_; ++t){
    // ======== P1: block = (rg 0..31) x (bg 0..3): rows rg*80..+80, batches bg*4..+4 ========
    {
      const int rg = blk & 31, bg = blk >> 5;
      float* hS = SH;   // 4 x 516 = 2064 floats (LDS-safe)
      {
        int i0 = tid*4; int bb = i0 >> 9, cc = i0 & 511;
        float vx,vy,vz,vw;
        if (t == 0){
          float4 v = *(const float4*)(p.inith + (size_t)(bg*4+bb)*512 + cc);
          vx=v.x; vy=v.y; vz=v.z; vw=v.w;
        } else {
          f32x4 v = ld_llc_f4(p.Hbuf + (size_t)(bg*4+bb)*512 + cc);
          vx=v[0]; vy=v[1]; vz=v[2]; vw=v[3];
        }
        hS[bb*516+cc]=vx; hS[bb*516+cc+1]=vy; hS[bb*516+cc+2]=vz; hS[bb*516+cc+3]=vw;
      }
      __syncthreads();
      int rl = tid >> 2, bl = tid & 3;
      if (rl < 80){
        int R = rg*80 + rl;
        const float* wrow = (R < 512) ? (p.Wq_c + (size_t)R*512)
                          : (R < 1024) ? (p.Wq_k + (size_t)(R-512)*512)
                          : (p.W_hh + (size_t)(R-1024)*512);
        const float* hb = hS + bl*516;
        float s = 0.f;
#pragma unroll 8
        for (int m=0;m<128;++m){
          float4 w = *(const float4*)(wrow + m*4);
          float4 hv = *(const float4*)(hb + m*4);
          s += w.x*hv.x + w.y*hv.y + w.z*hv.z + w.w*hv.w;
        }
        int b = bg*4 + bl;
        if (R < 512)       st_llc_f(p.HQC + b*512 + R, s);
        else if (R < 1024) st_llc_f(p.HQK + b*512 + (R-512), s);
        else               st_llc_f(p.GH + b*1536 + (R-1024), s + p.b_hh[R-1024]);
      }
    }
    pbar(p.cnt + (4*t)*BARSTRIDE_, blk);

    // ======== P2: e_src — block = (b 0..15) x (pg 0..7): positions pg*32..+32, 16 thr/row ========
    {
      const int b2 = blk >> 3, pg = blk & 7;
      float* hqcS = SH;        // 16 chunks x 33
      float* vwcS = SH + 528;
      {
        int q = tid >> 5, ii = tid & 31;
        if (tid < 512){
          hqcS[q*33+ii] = ld_llc_f(p.HQC + b2*512 + tid);
          vwcS[q*33+ii] = p.Vw_c[tid];
        }
      }
      __syncthreads();
      int pp = tid >> 4, q = tid & 15;
      int s_i = pg*32 + pp;
      const float4* pv4 = (const float4*)(p.PVS + ((size_t)(b2*S_ + s_i))*512 + q*32);
      const float* hq = hqcS + q*33;
      const float* vw = vwcS + q*33;
      float pe = 0.f;
#pragma unroll
      for (int m=0;m<8;++m){
        float4 v = pv4[m];
        int i0 = m*4;
        pe += ftanh(v.x+hq[i0+0])*vw[i0+0] + ftanh(v.y+hq[i0+1])*vw[i0+1]
            + ftanh(v.z+hq[i0+2])*vw[i0+2] + ftanh(v.w+hq[i0+3])*vw[i0+3];
      }
      pe += __shfl_down(pe, 8, 16);
      pe += __shfl_down(pe, 4, 16);
      pe += __shfl_down(pe, 2, 16);
      pe += __shfl_down(pe, 1, 16);
      if (q == 0){
        float v = pe + bVc;
        if (p.smask[b2*S_ + s_i] == 0.f) v += NEG_;
        st_llc_f(p.Eg + b2*S_ + s_i, v);
      }
    }
    pbar(p.cnt + (4*t+1)*BARSTRIDE_, blk);

    // ======== P3: softmax + c_t/k_t — block = (b 0..15) x (jg 0..7): cols jg*64..+64 ========
    {
      const int b3 = blk >> 3, jg = blk & 7, j0 = jg*64;
      float* eS    = SH;          // 256
      float* wS    = SH + 256;    // 256
      float* hqkS  = SH + 512;    // 64x9 = 576
      float* vwkS  = SH + 1088;   // 576
      float* partS = SH + 1664;   // 512
      float* ekS   = SH + 2176;   // 8
      float* kwS   = SH + 2184;   // 8
      float* MZ    = SH + 2192;   // 2
      if (tid < 64){
        f32x4 v = ld_llc_f4(p.Eg + b3*S_ + tid*4);
        eS[tid*4]=v[0]; eS[tid*4+1]=v[1]; eS[tid*4+2]=v[2]; eS[tid*4+3]=v[3];
      }
      {
        int part = tid >> 3, ii = tid & 7;
        hqkS[part*9+ii] = ld_llc_f(p.HQK + b3*512 + tid);
        vwkS[part*9+ii] = p.Vw_k[tid];
      }
      __syncthreads();
      if (tid < 64){
        float4 e4 = *(const float4*)&eS[tid*4];
        float m = fmaxf(fmaxf(e4.x,e4.y), fmaxf(e4.z,e4.w));
#pragma unroll
        for (int off=32; off>0; off>>=1) m = fmaxf(m, __shfl_xor(m, off, 64));
        float z = __expf(e4.x-m)+__expf(e4.y-m)+__expf(e4.z-m)+__expf(e4.w-m);
#pragma unroll
        for (int off=32; off>0; off>>=1) z += __shfl_xor(z, off, 64);
        if (tid == 0){ MZ[0] = m; MZ[1] = z; }
      }
      {
        int key = tid >> 6, part = tid & 63;
        const float4* pk4 = (const float4*)(p.PVK + ((size_t)(b3*K_ + key))*512 + part*8);
        float4 va = pk4[0], vb = pk4[1];
        const float* hq = hqkS + part*9;
        const float* vw = vwkS + part*9;
        float s2 = ftanh(va.x+hq[0])*vw[0] + ftanh(va.y+hq[1])*vw[1]
                 + ftanh(va.z+hq[2])*vw[2] + ftanh(va.w+hq[3])*vw[3]
                 + ftanh(vb.x+hq[4])*vw[4] + ftanh(vb.y+hq[5])*vw[5]
                 + ftanh(vb.z+hq[6])*vw[6] + ftanh(vb.w+hq[7])*vw[7];
#pragma unroll
        for (int off=32; off>0; off>>=1) s2 += __shfl_xor(s2, off, 64);
        if (part == 0){
          float v = s2 + bVk;
          if (p.kmask[b3*K_ + key] == 0.f) v += NEG_;
          ekS[key] = v;
        }
      }
      __syncthreads();
      if (tid == 0){
        float mk = -1e30f;
#pragma unroll
        for (int k=0;k<8;++k) mk = fmaxf(mk, ekS[k]);
        float z = 0.f; float tmp[8];
#pragma unroll
        for (int k=0;k<8;++k){ tmp[k] = __expf(ekS[k]-mk); z += tmp[k]; }
        float iz = 1.f/z;
#pragma unroll
        for (int k=0;k<8;++k) kwS[k] = tmp[k]*iz;
      }
      __syncthreads();
      float Mv = MZ[0], invZ = 1.f/MZ[1];
      if (tid < 256) wS[tid] = __expf(eS[tid]-Mv);
      __syncthreads();
      {
        int sg = tid >> 6, jl = tid & 63;
        const float* sp = p.src + ((size_t)(b3*S_ + sg*32))*512 + j0 + jl;
        float acc = 0.f;
#pragma unroll 8
        for (int i=0;i<32;++i) acc += wS[sg*32+i] * sp[(size_t)i*512];
        partS[sg*64 + jl] = acc;
      }
      __syncthreads();
      if (tid < 64){
        float c = 0.f;
#pragma unroll
        for (int sg=0; sg<8; ++sg) c += partS[sg*64 + tid];
        c *= invZ;
        float kt = 0.f;
#pragma unroll
        for (int k=0;k<8;++k) kt += kwS[k] * p.kgh[((size_t)(b3*K_+k))*512 + j0 + tid];
        float* Xbt = p.Xb + ((size_t)t*16 + b3)*1536;
        Xbt[512 + j0 + tid]  = c;
        Xbt[1024 + j0 + tid] = kt;
        st_llc_f(p.CK + b3*1024 + j0 + tid, c);
        st_llc_f(p.CK + b3*1024 + 512 + j0 + tid, kt);
      }
      if (jg == 0 && tid < 8) p.KW[t*128 + b3*8 + tid] = kwS[tid];
    }
    pbar(p.cnt + (4*t+2)*BARSTRIDE_, blk);

    // ======== P4: GRU — block = (rg2 0..31) x (bg2 0..3): cols rg2*16..+16, batches bg2*4..+4 ========
    {
      const int rg2 = blk & 31, bg2 = blk >> 5;
      const int j0 = rg2*16, bb0 = bg2*4;
      float* ckS = SH;          // 4 x 1028
      float* giS = SH + 4112;   // 48 x 4
      float* ghS = SH + 4304;   // 48 x 4
      {
        int i0 = tid*8; int bb = i0 >> 10, cc = i0 & 1023;
        f32x4 a, b4;
        ld_llc_f4x2(p.CK + (size_t)(bb0+bb)*1024 + cc, a, b4);
        float* d = ckS + bb*1028 + cc;
        d[0]=a[0]; d[1]=a[1]; d[2]=a[2]; d[3]=a[3];
        d[4]=b4[0]; d[5]=b4[1]; d[6]=b4[2]; d[7]=b4[3];
      }
      __syncthreads();
      int pair = tid >> 1, ks = tid & 1;
      float gi = 0.f;
      int row = 0, bloc = 0, rw = 0;
      if (pair < 192){
        rw = pair >> 2; bloc = pair & 3;
        row = (rw >> 4)*512 + j0 + (rw & 15);
        const float4* wi4 = (const float4*)(p.W_ih + (size_t)row*1536 + 512 + ks*512);
        const float* ckb = ckS + bloc*1028 + ks*512;
#pragma unroll 8
        for (int m=0;m<128;++m){
          float4 w = wi4[m];
          gi += w.x*ckb[m*4] + w.y*ckb[m*4+1] + w.z*ckb[m*4+2] + w.w*ckb[m*4+3];
        }
      }
      gi += __shfl_xor(gi, 1, 64);
      if (pair < 192 && ks == 0){
        int b = bb0 + bloc;
        giS[rw*4 + bloc] = gi + p.GIY[((size_t)t*16 + b)*1536 + row] + p.b_ih[row];
        ghS[rw*4 + bloc] = ld_llc_f(p.GH + b*1536 + row);
      }
      __syncthreads();
      if (tid < 64){
        int jl = tid >> 2, bl2 = tid & 3;
        int b = bb0 + bl2, j = j0 + jl;
        float gir = giS[jl*4+bl2],      giz = giS[(16+jl)*4+bl2],  gin = giS[(32+jl)*4+bl2];
        float ghr = ghS[jl*4+bl2],      ghz = ghS[(16+jl)*4+bl2],  ghn = ghS[(32+jl)*4+bl2];
        float r = fsigmoid(gir + ghr);
        float z = fsigmoid(giz + ghz);
        float n = ftanh(gin + r*ghn);
        float hold = (t == 0) ? p.inith[b*512 + j] : ld_llc_f(p.Hbuf + b*512 + j);
        float hn = (1.f - z)*n + z*hold;
        p.S_all[((size_t)t*16 + b)*512 + j] = hn;
        st_llc_f(p.Hbuf + b*512 + j, hn);
      }
    }
    pbar(p.cnt + (4*t+3)*BARSTRIDE_, blk);
  }
}

// ================= merged epilogue-1: W1-GEMM(CAT-gather) ∥ Qb-GEMM ∥ ptr =================
__global__ __launch_bounds__(256) void k_epi(const float* __restrict__ S_all, const float* __restrict__ X,
    const float* __restrict__ kgf, const float* __restrict__ W1, const float* __restrict__ b1,
    const float* __restrict__ Wcpy, const float* __restrict__ bcpy,
    const float* __restrict__ Wptr, const float* __restrict__ bptr,
    float* __restrict__ HID, float* __restrict__ Qb, float* __restrict__ PTR){
  const int bid = blockIdx.x, tid = threadIdx.x;
  if (bid >= 64){   // ptr: rows (bid-64)*4 .. +4
    int r = (bid-64)*4 + (tid >> 6);
    int lane = tid & 63;
    const float* seg[5];
    seg[0] = X + (size_t)r*1536 + 512;
    seg[1] = S_all + (size_t)r*512;
    seg[2] = X + (size_t)r*1536;
    seg[3] = kgf + (size_t)(r & 15)*512;
    seg[4] = X + (size_t)r*1536 + 1024;
    float s = 0.f;
#pragma unroll
    for (int g=0; g<5; ++g){
      const float* p = seg[g];
      const float* w = Wptr + g*512;
#pragma unroll
      for (int m=0;m<8;++m){ int i = lane + m*64; s += p[i]*w[i]; }
    }
#pragma unroll
    for (int off=32;off>0;off>>=1) s += __shfl_down(s, off, 64);
    if (lane == 0) PTR[r] = fsigmoid(s + bptr[0]);
    return;
  }
  __shared__ float As[16][132];
  __shared__ float Ws[16][68];
  const bool isW1 = (bid < 32);
  const int g = isW1 ? bid : bid-32;
  const int m0 = (g&3)*128, n0 = (g>>2)*64;
  const int KK = isW1 ? 2048 : 512;
  const float* W = isW1 ? W1 : Wcpy;
  const float* bias = isW1 ? b1 : bcpy;
  float* C = isW1 ? HID : Qb;
  const int tm = tid & 15, tn = tid >> 4;
  float acc[8][4];
#pragma unroll
  for (int i=0;i<8;++i)
#pragma unroll
    for(int j=0;j<4;++j) acc[i][j]=0.f;
  for (int k0=0;k0<KK;k0+=16){
#pragma unroll
    for (int rr=0;rr<2;++rr){
      int f = tid + rr*256;
      int mm = f >> 2, kc = f & 3;
      int m = m0 + mm, col = k0 + kc*4;
      const float* ap;
      if (!isW1)            ap = S_all + (size_t)m*512 + col;
      else if (col < 512)   ap = S_all + (size_t)m*512 + col;
      else if (col < 1536)  ap = X + (size_t)m*1536 + col;
      else                  ap = kgf + (size_t)(m & 15)*512 + (col - 1536);
      const float4 v = *(const float4*)ap;
      As[kc*4+0][mm]=v.x; As[kc*4+1][mm]=v.y; As[kc*4+2][mm]=v.z; As[kc*4+3][mm]=v.w;
    }
    {
      int nn = tid >> 2, kc = tid & 3;
      const float4 v = *(const float4*)(W + (size_t)(n0+nn)*KK + k0 + kc*4);
      Ws[kc*4+0][nn]=v.x; Ws[kc*4+1][nn]=v.y; Ws[kc*4+2][nn]=v.z; Ws[kc*4+3][nn]=v.w;
    }
    __syncthreads();
#pragma unroll
    for (int kk=0;kk<16;++kk){
      float a[8], w[4];
      float4 a0 = *(const float4*)&As[kk][tm*8];
      float4 a1 = *(const float4*)&As[kk][tm*8+4];
      float4 w0 = *(const float4*)&Ws[kk][tn*4];
      a[0]=a0.x;a[1]=a0.y;a[2]=a0.z;a[3]=a0.w;a[4]=a1.x;a[5]=a1.y;a[6]=a1.z;a[7]=a1.w;
      w[0]=w0.x;w[1]=w0.y;w[2]=w0.z;w[3]=w0.w;
#pragma unroll
      for (int i=0;i<8;++i)
#pragma unroll
        for (int j=0;j<4;++j) acc[i][j] += a[i]*w[j];
    }
    __syncthreads();
  }
#pragma unroll
  for (int i=0;i<8;++i){
    int m = m0 + tm*8 + i;
#pragma unroll
    for (int j=0;j<4;++j){
      int n = n0 + tn*4 + j;
      C[(size_t)m*512 + n] = acc[i][j] + bias[n];
    }
  }
}

// ============ bf16 MFMA logits GEMM, f32 inputs converted inline (verified) ============
__global__ __launch_bounds__(512) void k_logits(const float* __restrict__ A,
    const float* __restrict__ Bf, const float* __restrict__ bias, float* __restrict__ out){
  __shared__ unsigned short As[256][72];
  __shared__ unsigned short Bs[128][72];
  const int tid = threadIdx.x;
  const int m0 = blockIdx.x*256, n0 = blockIdx.y*128;
  const int lane = tid & 63, wid = tid >> 6;
  const int mw = wid >> 1, nw = wid & 1;
  f32x4 acc[4][4];
#pragma unroll
  for (int i=0;i<4;++i)
#pragma unroll
    for (int j=0;j<4;++j) acc[i][j] = (f32x4){0.f,0.f,0.f,0.f};
  for (int k0 = 0; k0 < 512; k0 += 64){
#pragma unroll
    for (int i=0;i<4;++i){
      int v = i*512 + tid; int row = v >> 3, vc = v & 7;
      const float* srcp = A + (size_t)(m0+row)*512 + k0 + vc*8;
      float4 f0 = *(const float4*)srcp, f1 = *(const float4*)(srcp+4);
      us8 d;
      d[0]=bf16rne(f0.x); d[1]=bf16rne(f0.y); d[2]=bf16rne(f0.z); d[3]=bf16rne(f0.w);
      d[4]=bf16rne(f1.x); d[5]=bf16rne(f1.y); d[6]=bf16rne(f1.z); d[7]=bf16rne(f1.w);
      *(us8*)&As[row][vc*8] = d;
    }
#pragma unroll
    for (int i=0;i<2;++i){
      int v = i*512 + tid; int row = v >> 3, vc = v & 7;
      const float* srcp = Bf + (size_t)(n0+row)*512 + k0 + vc*8;
      float4 f0 = *(const float4*)srcp, f1 = *(const float4*)(srcp+4);
      us8 d;
      d[0]=bf16rne(f0.x); d[1]=bf16rne(f0.y); d[2]=bf16rne(f0.z); d[3]=bf16rne(f0.w);
      d[4]=bf16rne(f1.x); d[5]=bf16rne(f1.y); d[6]=bf16rne(f1.z); d[7]=bf16rne(f1.w);
      *(us8*)&Bs[row][vc*8] = d;
    }
    __syncthreads();
#pragma unroll
    for (int kk=0;kk<2;++kk){
      bf16x8 a[4], bf[4];
#pragma unroll
      for (int mi=0;mi<4;++mi){
        int ar = mw*64 + mi*16 + (lane&15);
        a[mi] = *(const bf16x8*)&As[ar][(kk*4 + (lane>>4))*8];
      }
#pragma unroll
      for (int ni=0;ni<4;++ni){
        int br = nw*64 + ni*16 + (lane&15);
        bf[ni] = *(const bf16x8*)&Bs[br][(kk*4 + (lane>>4))*8];
      }
#pragma unroll
      for (int mi=0;mi<4;++mi)
#pragma unroll
        for (int ni=0;ni<4;++ni)
          acc[mi][ni] = __builtin_amdgcn_mfma_f32_16x16x32_bf16(a[mi], bf[ni], acc[mi][ni], 0, 0, 0);
    }
    __syncthreads();
  }
#pragma unroll
  for (int mi=0;mi<4;++mi){
#pragma unroll
    for (int r=0;r<4;++r){
      int gr = m0 + mw*64 + mi*16 + (lane>>4)*4 + r;
      size_t orow = (size_t)((gr&15)*32 + (gr>>4)) * VX_;
#pragma unroll
      for (int ni=0;ni<4;++ni){
        int col = n0 + nw*64 + ni*16 + (lane&15);
        out[orow + col] = acc[mi][ni][r] + bias[col];
      }
    }
  }
}

// ============ fused online-softmax + copy-scatter (2 passes over V; no final norm) ============
__global__ __launch_bounds__(256) void k_final(float* __restrict__ out, const float* __restrict__ PTR,
    const float* __restrict__ Q, const float* __restrict__ kgo, const float* __restrict__ kpmask,
    const int* __restrict__ kev, const float* __restrict__ KW){
  const int orow = blockIdx.x;
  const int b = orow >> 5, t = orow & 31;
  const int r = t*16 + b;
  const int tid = threadIdx.x;
  float* f = out + (size_t)orow * VX_;
  __shared__ float qs[512];
  __shared__ float part[256];
  __shared__ float red[256];
  __shared__ float valS[512];
  __shared__ int   idxS[512];
  const float ptr = PTR[r];
  qs[tid] = Q[(size_t)r*512 + tid];
  qs[256 + tid] = Q[(size_t)r*512 + 256 + tid];
  __syncthreads();
  for (int k = 0; k < 8; ++k){
    int l = tid >> 2, qtr = tid & 3;
    const float* kgrow = kgo + (size_t)((b*8 + k)*64 + l) * 512;
    float p = 0.f;
    const float4* q4 = (const float4*)(qs) + qtr*32;
    const float4* k4 = (const float4*)(kgrow) + qtr*32;
#pragma unroll 4
    for (int m=0;m<32;++m){ float4 a=q4[m], c=k4[m]; p += a.x*c.x+a.y*c.y+a.z*c.z+a.w*c.w; }
    part[tid] = p;
    __syncthreads();
    if (tid < 64){
      float ev = part[tid*4]+part[tid*4+1]+part[tid*4+2]+part[tid*4+3];
      if (kpmask[(b*8+k)*64 + tid] == 0.f) ev += NEG_;
      float mx = ev;
#pragma unroll
      for (int off=32;off>0;off>>=1) mx = fmaxf(mx, __shfl_xor(mx, off, 64));
      float ex = __expf(ev - mx);
      float z = ex;
#pragma unroll
      for (int off=32;off>0;off>>=1) z += __shfl_xor(z, off, 64);
      valS[k*64 + tid] = (ex/z) * KW[t*128 + b*8 + k] * (1.f - ptr);
      idxS[k*64 + tid] = kev[(b*8+k)*64 + tid];
    }
    __syncthreads();
  }
  // online softmax: pass 1 computes (max, sum) in one read; pass 2 writes exp*scale
  float* redm = qs;   // qs is dead after the copy-dist loop — reuse first 256 as max buffer
  float m = -1e30f, s = 0.f;
  for (int v = tid; v < V_; v += 256){
    float x = f[v];
    float nm = fmaxf(m, x);
    s = s*__expf(m - nm) + __expf(x - nm);
    m = nm;
  }
  redm[tid] = m; red[tid] = s;
  __syncthreads();
  for (int st = 128; st > 0; st >>= 1){
    if (tid < st){
      float m2 = redm[tid+st], s2 = red[tid+st];
      float M2 = fmaxf(redm[tid], m2);
      red[tid] = red[tid]*__expf(redm[tid]-M2) + s2*__expf(m2-M2);
      redm[tid] = M2;
    }
    __syncthreads();
  }
  float M = redm[0];
  float scale = ptr / red[0];
  for (int v = tid; v < V_; v += 256) f[v] = __expf(f[v]-M) * scale;
  for (int v = V_ + tid; v < VX_; v += 256) f[v] = 0.f;
  __syncthreads();
  atomicAdd(f + idxS[tid], valS[tid]);
  atomicAdd(f + idxS[256 + tid], valS[256 + tid]);
}

extern "C" void kernel_launch(void* const* d_in, const int* in_sizes, int n_in,
                              void* d_out, int out_size, void* d_ws, size_t ws_size,
                              hipStream_t stream) {
  const int*   tgt   = (const int*)  d_in[0];
  const float* inith = (const float*)d_in[1];
  const float* src   = (const float*)d_in[2];
  const float* smask = (const float*)d_in[3];
  const float* kgh   = (const float*)d_in[4];
  const float* kgf   = (const float*)d_in[5];
  const float* kgo   = (const float*)d_in[6];
  const float* kmask = (const float*)d_in[7];
  const float* kpmask= (const float*)d_in[8];
  const int*   kev   = (const int*)  d_in[10];
  const float* emb   = (const float*)d_in[12];
  const float* W_ih  = (const float*)d_in[13];
  const float* W_hh  = (const float*)d_in[14];
  const float* b_ih  = (const float*)d_in[15];
  const float* b_hh  = (const float*)d_in[16];
  const float* Wq_c  = (const float*)d_in[17];
  const float* Wv_c  = (const float*)d_in[18];
  const float* bv_c  = (const float*)d_in[19];
  const float* Vw_c  = (const float*)d_in[20];
  const float* bV_c  = (const float*)d_in[21];
  const float* Wq_k  = (const float*)d_in[22];
  const float* Wv_k  = (const float*)d_in[23];
  const float* bv_k  = (const float*)d_in[24];
  const float* Vw_k  = (const float*)d_in[25];
  const float* bV_k  = (const float*)d_in[26];
  const float* W1    = (const float*)d_in[27];
  const float* b1    = (const float*)d_in[28];
  const float* W2    = (const float*)d_in[29];
  const float* b2    = (const float*)d_in[30];
  const float* Wptr  = (const float*)d_in[31];
  const float* bptr  = (const float*)d_in[32];
  const float* Wcpy  = (const float*)d_in[33];
  const float* bcpy  = (const float*)d_in[34];
  float* out = (float*)d_out;

  float* Xb    = (float*)d_ws;            // (T,B,1536)
  float* S_all = Xb    + 786432;          // (T*B,512)
  float* PVS   = S_all + 262144;          // (B,S,512)
  float* PVK   = PVS   + 2097152;         // (B,8,512)
  float* KW    = PVK   + 65536;           // (T,B,8)
  float* GIY   = KW    + 4096;            // (T*B,1536)
  float* CK    = GIY   + 786432;          // (16,1024)
  float* HID   = CK    + 16384;           // (512,512)
  float* Qb    = HID   + 262144;          // (512,512)
  float* PTR   = Qb    + 262144;          // (512)
  float* HQC   = PTR   + 512;             // (16,512)
  float* HQK   = HQC   + 8192;            // (16,512)
  float* GH    = HQK   + 8192;            // (16,1536)
  float* Hbuf  = GH    + 24576;           // (16,512)
  float* Eg    = Hbuf  + 8192;            // (16,256)
  unsigned* CNT = (unsigned*)(Eg + 4096); // 128 instances x 128 u32 (4 groups x 2 lines)

  hipMemsetAsync(CNT, 0, 128*BARSTRIDE_*sizeof(unsigned), stream);

  // merged prep: embed ∥ PVS ∥ PVK ∥ GIY
  k_prep<<<1384, 256, 0, stream>>>(emb, tgt, src, Wv_c, bv_c, kgh, Wv_k, bv_k, W_ih,
                                   Xb, PVS, PVK, GIY);

  // persistent recurrence: v4 phases + per-group (32-block) barriers
  RP4 rp { inith, src, smask, kgh, kmask, Wq_c, Wq_k, Vw_c, bV_c, Vw_k, bV_k,
           W_ih, W_hh, b_ih, b_hh, PVS, PVK, GIY, Xb, S_all, KW,
           HQC, HQK, GH, CK, Hbuf, Eg, CNT };
  k_recur4<<<NBLK_, 512, 0, stream>>>(rp);

  // merged epilogue-1: W1-GEMM(CAT) ∥ Qb-GEMM ∥ ptr
  k_epi<<<192, 256, 0, stream>>>(S_all, Xb, kgf, W1, b1, Wcpy, bcpy, Wptr, bptr, HID, Qb, PTR);
  // bf16 MFMA logits
  k_logits<<<dim3(2,250), 512, 0, stream>>>(HID, W2, b2, out);
  // fused online-softmax + scatter (no norm)
  k_final<<<512, 256, 0, stream>>>(out, PTR, Qb, kgo, kpmask, kev, KW);
}